// Round 1
// baseline (529.495 us; speedup 1.0000x reference)
//
#include <hip/hip_runtime.h>
#include <cmath>

#define B_    16
#define HH    56
#define WWI   56
#define C_    256
#define NH_   8
#define WS_   7
#define SS_   3
#define HD_   32
#define NTOK  50176          // B*56*56
#define NN    49             // window size squared
#define SCALE_ 0.17677669529663689f
#define EPS_  1e-5f

typedef __bf16  bf16x8  __attribute__((ext_vector_type(8)));
typedef float   f32x4   __attribute__((ext_vector_type(4)));
typedef unsigned short ushort8v __attribute__((ext_vector_type(8)));

__device__ __forceinline__ unsigned short f2bf(float f) {
    unsigned int u = __float_as_uint(f);
    unsigned int r = u + 0x7FFFu + ((u >> 16) & 1u);   // RNE
    return (unsigned short)(r >> 16);
}
__device__ __forceinline__ float bf2f(unsigned short h) {
    return __uint_as_float(((unsigned int)h) << 16);
}

// ---------------- weight fp32 -> bf16 conversion ----------------
__global__ __launch_bounds__(256) void convw_k(
    const float* __restrict__ qkvw, const float* __restrict__ projw,
    const float* __restrict__ fc1w, const float* __restrict__ fc2w,
    unsigned short* __restrict__ dst)
{
    int i = blockIdx.x * 256 + threadIdx.x;          // < 786432
    float v;
    if      (i < 196608) v = qkvw[i];
    else if (i < 262144) v = projw[i - 196608];
    else if (i < 524288) v = fc1w[i - 262144];
    else                 v = fc2w[i - 524288];
    dst[i] = f2bf(v);
}

// ---------------- LayerNorm (+optional shift+window-partition) ----------------
// one wave per token; lane handles 4 channels
__global__ __launch_bounds__(256) void ln_k(
    const float* __restrict__ x, const float* __restrict__ g,
    const float* __restrict__ bta, unsigned short* __restrict__ dst, int shifted)
{
    int wave = threadIdx.x >> 6, lane = threadIdx.x & 63;
    int tok = blockIdx.x * 4 + wave;                  // < 50176
    const float4 v = *(const float4*)(x + (size_t)tok * C_ + lane * 4);
    float s = v.x + v.y + v.z + v.w;
    float q = v.x*v.x + v.y*v.y + v.z*v.z + v.w*v.w;
    for (int o = 32; o > 0; o >>= 1) { s += __shfl_xor(s, o, 64); q += __shfl_xor(q, o, 64); }
    float mu  = s * (1.0f / C_);
    float var = q * (1.0f / C_) - mu * mu;
    float rs  = rsqrtf(var + EPS_);
    float4 gg = *(const float4*)(g   + lane * 4);
    float4 bb = *(const float4*)(bta + lane * 4);
    float y0 = (v.x - mu) * rs * gg.x + bb.x;
    float y1 = (v.y - mu) * rs * gg.y + bb.y;
    float y2 = (v.z - mu) * rs * gg.z + bb.z;
    float y3 = (v.w - mu) * rs * gg.w + bb.w;
    size_t di;
    if (shifted) {
        int b = tok / 3136, p = tok % 3136;
        int ph = p / 56, pw = p % 56;
        int sh = ph - SS_; if (sh < 0) sh += HH;
        int sw = pw - SS_; if (sw < 0) sw += WWI;
        int bw = b * 64 + (sh / WS_) * 8 + (sw / WS_);
        int n  = (sh % WS_) * WS_ + (sw % WS_);
        di = ((size_t)bw * NN + n) * C_ + lane * 4;
    } else {
        di = (size_t)tok * C_ + lane * 4;
    }
    unsigned int lo = (unsigned int)f2bf(y0) | ((unsigned int)f2bf(y1) << 16);
    unsigned int hi = (unsigned int)f2bf(y2) | ((unsigned int)f2bf(y3) << 16);
    uint2 u; u.x = lo; u.y = hi;
    *(uint2*)(dst + di) = u;
}

// ---------------- MFMA GEMM, 128x128 tile, BK=32 ----------------
// A: (M,K) bf16 row-major.  Bt: (N,K) bf16 row-major (== B^T, matches weight layout).
// EPI: 0 = QKV scatter, 1 = proj + window-reverse + residual, 2 = GELU, 3 = FC2 + residual RMW
template<int EPI>
__global__ __launch_bounds__(256) void gemm_k(
    const unsigned short* __restrict__ A, const unsigned short* __restrict__ Bt,
    int K, const float* __restrict__ bias,
    const float* __restrict__ resid, float* __restrict__ outF,
    unsigned short* __restrict__ outQ, unsigned short* __restrict__ outK,
    unsigned short* __restrict__ outV)
{
    __shared__ unsigned short lA[128][40];  // pad 40 -> 80B row stride (20 banks): 2-way, free
    __shared__ unsigned short lB[128][40];
    const int tid = threadIdx.x;
    const int m0 = blockIdx.y * 128, n0 = blockIdx.x * 128;
    const int wave = tid >> 6, lane = tid & 63, quad = lane >> 4, l16 = lane & 15;
    const int wm = wave >> 1, wn = wave & 1;
    const int srow = tid >> 1, scol = (tid & 1) * 16;

    f32x4 acc[4][4] = {};
    const int nk = K >> 5;
    for (int kk = 0; kk < nk; ++kk) {
        const int k0 = kk << 5;
        {
            size_t ga = (size_t)(m0 + srow) * K + k0 + scol;
            uint4 a0 = *(const uint4*)(A + ga);
            uint4 a1 = *(const uint4*)(A + ga + 8);
            size_t gb = (size_t)(n0 + srow) * K + k0 + scol;
            uint4 b0 = *(const uint4*)(Bt + gb);
            uint4 b1 = *(const uint4*)(Bt + gb + 8);
            *(uint4*)&lA[srow][scol]     = a0;
            *(uint4*)&lA[srow][scol + 8] = a1;
            *(uint4*)&lB[srow][scol]     = b0;
            *(uint4*)&lB[srow][scol + 8] = b1;
        }
        __syncthreads();
        bf16x8 af[4], bf[4];
        #pragma unroll
        for (int t = 0; t < 4; ++t) {
            af[t] = __builtin_bit_cast(bf16x8, *(const ushort8v*)&lA[wm * 64 + t * 16 + l16][quad * 8]);
            bf[t] = __builtin_bit_cast(bf16x8, *(const ushort8v*)&lB[wn * 64 + t * 16 + l16][quad * 8]);
        }
        #pragma unroll
        for (int mt = 0; mt < 4; ++mt)
            #pragma unroll
            for (int nt = 0; nt < 4; ++nt)
                acc[mt][nt] = __builtin_amdgcn_mfma_f32_16x16x32_bf16(af[mt], bf[nt], acc[mt][nt], 0, 0, 0);
        __syncthreads();
    }

    #pragma unroll
    for (int mt = 0; mt < 4; ++mt) {
        #pragma unroll
        for (int nt = 0; nt < 4; ++nt) {
            #pragma unroll
            for (int r = 0; r < 4; ++r) {
                int m = m0 + wm * 64 + mt * 16 + quad * 4 + r;
                int n = n0 + wn * 64 + nt * 16 + l16;
                float v = acc[mt][nt][r] + bias[n];
                if (EPI == 0) {            // QKV: scatter to q/k/v (bw, head, n, hd), q scaled
                    int c = n & 255;
                    int head = c >> 5, hd = c & 31;
                    int bw = m / NN, nw = m % NN;
                    size_t o = ((size_t)(bw * NH_ + head) * NN + nw) * HD_ + hd;
                    if      (n < 256) outQ[o] = f2bf(v * SCALE_);
                    else if (n < 512) outK[o] = f2bf(v);
                    else              outV[o] = f2bf(v);
                } else if (EPI == 1) {     // proj: window-reverse + unshift + residual -> x2 (d_out)
                    int bw = m / NN, nw = m % NN;
                    int b = bw >> 6, wi = bw & 63;
                    int sh = (wi >> 3) * WS_ + nw / WS_;
                    int sw = (wi & 7) * WS_ + nw % WS_;
                    int ph = sh + SS_; if (ph >= HH)  ph -= HH;
                    int pw = sw + SS_; if (pw >= WWI) pw -= WWI;
                    size_t t = ((size_t)b * 3136 + ph * 56 + pw) * C_ + n;
                    outF[t] = resid[t] + v;
                } else if (EPI == 2) {     // FC1 + exact GELU -> a1 bf16
                    float gl = 0.5f * v * (1.0f + erff(v * 0.70710678118654752f));
                    outQ[(size_t)m * 1024 + n] = f2bf(gl);
                } else {                   // FC2 + residual (d_out holds x2)
                    size_t t = (size_t)m * C_ + n;
                    outF[t] = outF[t] + v;
                }
            }
        }
    }
}

// ---------------- attention: one block per (window, head) ----------------
__global__ __launch_bounds__(256) void attn_k(
    const unsigned short* __restrict__ qb, const unsigned short* __restrict__ kb,
    const unsigned short* __restrict__ vb, const float* __restrict__ mask,
    const float* __restrict__ relb, unsigned short* __restrict__ ob)
{
    __shared__ float qs[NN][34], ks[NN][34], vs[NN][34];  // pad 34: float2 reads 2-way free
    __shared__ float sc[NN * NN];
    int bw = blockIdx.x >> 3, head = blockIdx.x & 7;
    int tid = threadIdx.x;
    size_t base = ((size_t)bw * NH_ + head) * NN * HD_;
    for (int i = tid; i < NN * HD_; i += 256) {
        int r = i >> 5, c = i & 31;
        qs[r][c] = bf2f(qb[base + i]);
        ks[r][c] = bf2f(kb[base + i]);
        vs[r][c] = bf2f(vb[base + i]);
    }
    __syncthreads();
    const float* mrow = mask + (size_t)(bw & 63) * NN * NN;
    for (int p = tid; p < NN * NN; p += 256) {
        int i = p / NN, j = p - i * NN;
        float s = 0.0f;
        #pragma unroll
        for (int kk = 0; kk < HD_; kk += 2) {
            float2 a = *(const float2*)&qs[i][kk];
            float2 b = *(const float2*)&ks[j][kk];
            s += a.x * b.x + a.y * b.y;
        }
        int di = i / 7 - j / 7 + 6, dj = i % 7 - j % 7 + 6;
        sc[p] = s + relb[(di * 13 + dj) * NH_ + head] + mrow[p];
    }
    __syncthreads();
    if (tid < NN) {
        float* row = &sc[tid * NN];
        float mx = -1e30f;
        for (int j = 0; j < NN; ++j) mx = fmaxf(mx, row[j]);
        float sum = 0.0f;
        for (int j = 0; j < NN; ++j) { float e = __expf(row[j] - mx); row[j] = e; sum += e; }
        float inv = 1.0f / sum;
        for (int j = 0; j < NN; ++j) row[j] *= inv;
    }
    __syncthreads();
    for (int p = tid; p < NN * 16; p += 256) {         // 784 (i, d-pair) tasks
        int i = p >> 4, d2 = (p & 15) * 2;
        float o0 = 0.0f, o1 = 0.0f;
        for (int j = 0; j < NN; ++j) {
            float pj = sc[i * NN + j];
            float2 vv = *(const float2*)&vs[j][d2];
            o0 += pj * vv.x; o1 += pj * vv.y;
        }
        unsigned int pk = (unsigned int)f2bf(o0) | ((unsigned int)f2bf(o1) << 16);
        *(unsigned int*)&ob[((size_t)bw * NN + i) * C_ + head * HD_ + d2] = pk;
    }
}

extern "C" void kernel_launch(void* const* d_in, const int* in_sizes, int n_in,
                              void* d_out, int out_size, void* d_ws, size_t ws_size,
                              hipStream_t stream)
{
    const float* x     = (const float*)d_in[0];
    const float* mask  = (const float*)d_in[1];
    const float* n1g   = (const float*)d_in[2];
    const float* n1b   = (const float*)d_in[3];
    const float* qkvw  = (const float*)d_in[4];
    const float* qkvb  = (const float*)d_in[5];
    const float* relb  = (const float*)d_in[6];
    const float* projw = (const float*)d_in[7];
    const float* projb = (const float*)d_in[8];
    const float* n2g   = (const float*)d_in[9];
    const float* n2b   = (const float*)d_in[10];
    const float* fc1w  = (const float*)d_in[11];
    const float* fc1b  = (const float*)d_in[12];
    const float* fc2w  = (const float*)d_in[13];
    const float* fc2b  = (const float*)d_in[14];
    float* out = (float*)d_out;

    unsigned short* wq = (unsigned short*)d_ws;   // all weights bf16, contiguous
    unsigned short* wp = wq + 196608;
    unsigned short* w1 = wq + 262144;
    unsigned short* w2 = wq + 524288;
    unsigned short* hw = wq + 786432;             // LN1-shift-partitioned (50176,256) bf16
    unsigned short* qb = hw + 12845056;           // (1024,8,49,32) bf16
    unsigned short* kb = qb + 12845056;
    unsigned short* vb = kb + 12845056;
    unsigned short* ob = vb + 12845056;           // attn out, windowed (50176,256) bf16
    unsigned short* h2 = ob + 12845056;           // LN2 out (50176,256) bf16
    unsigned short* a1 = h2 + 12845056;           // GELU(fc1) (50176,1024) bf16

    convw_k<<<3072, 256, 0, stream>>>(qkvw, projw, fc1w, fc2w, wq);
    ln_k<<<12544, 256, 0, stream>>>(x, n1g, n1b, hw, 1);
    gemm_k<0><<<dim3(6, 392), 256, 0, stream>>>(hw, wq, 256, qkvb, nullptr, nullptr, qb, kb, vb);
    attn_k<<<8192, 256, 0, stream>>>(qb, kb, vb, mask, relb, ob);
    gemm_k<1><<<dim3(2, 392), 256, 0, stream>>>(ob, wp, 256, projb, x, out, nullptr, nullptr, nullptr);
    ln_k<<<12544, 256, 0, stream>>>(out, n2g, n2b, h2, 0);
    gemm_k<2><<<dim3(8, 392), 256, 0, stream>>>(h2, w1, 256, fc1b, nullptr, nullptr, a1, nullptr, nullptr);
    gemm_k<3><<<dim3(2, 392), 256, 0, stream>>>(a1, w2, 1024, fc2b, nullptr, out, nullptr, nullptr, nullptr);
}

// Round 2
// 442.997 us; speedup vs baseline: 1.1953x; 1.1953x over previous
//
#include <hip/hip_runtime.h>
#include <cmath>

#define B_    16
#define HH    56
#define WWI   56
#define C_    256
#define NH_   8
#define WS_   7
#define SS_   3
#define HD_   32
#define NTOK  50176          // B*56*56
#define NN    49             // window size squared
#define SCALE_ 0.17677669529663689f
#define EPS_  1e-5f

typedef __bf16  bf16x8  __attribute__((ext_vector_type(8)));
typedef float   f32x4   __attribute__((ext_vector_type(4)));
typedef unsigned short ushort8v __attribute__((ext_vector_type(8)));

__device__ __forceinline__ unsigned short f2bf(float f) {
    unsigned int u = __float_as_uint(f);
    unsigned int r = u + 0x7FFFu + ((u >> 16) & 1u);   // RNE
    return (unsigned short)(r >> 16);
}
__device__ __forceinline__ float bf2f(unsigned short h) {
    return __uint_as_float(((unsigned int)h) << 16);
}

// ---------------- weight fp32 -> bf16 conversion ----------------
__global__ __launch_bounds__(256) void convw_k(
    const float* __restrict__ qkvw, const float* __restrict__ projw,
    const float* __restrict__ fc1w, const float* __restrict__ fc2w,
    unsigned short* __restrict__ dst)
{
    int i = blockIdx.x * 256 + threadIdx.x;          // < 786432
    float v;
    if      (i < 196608) v = qkvw[i];
    else if (i < 262144) v = projw[i - 196608];
    else if (i < 524288) v = fc1w[i - 262144];
    else                 v = fc2w[i - 524288];
    dst[i] = f2bf(v);
}

// ---------------- combined rel-bias + shift-mask table, bf16 ----------------
// cb[(wi*8+head)*2408 + i*49 + j] = relb[rel_idx(i,j)][head] + mask[wi][i][j]
__global__ __launch_bounds__(256) void cb_k(
    const float* __restrict__ mask, const float* __restrict__ relb,
    unsigned short* __restrict__ cb)
{
    int s = blockIdx.x;                 // 512 slices = 64 windows * 8 heads
    int wi = s >> 3, head = s & 7;
    for (int p = threadIdx.x; p < 2408; p += 256) {
        float v = 0.0f;
        if (p < 2401) {
            int i = p / NN, j = p - i * NN;
            int di = i / 7 - j / 7 + 6, dj = i % 7 - j % 7 + 6;
            v = relb[(di * 13 + dj) * NH_ + head] + mask[(size_t)wi * 2401 + p];
        }
        cb[(size_t)s * 2408 + p] = f2bf(v);
    }
}

// ---------------- LayerNorm (+optional shift+window-partition) ----------------
__global__ __launch_bounds__(256) void ln_k(
    const float* __restrict__ x, const float* __restrict__ g,
    const float* __restrict__ bta, unsigned short* __restrict__ dst, int shifted)
{
    int wave = threadIdx.x >> 6, lane = threadIdx.x & 63;
    int tok = blockIdx.x * 4 + wave;                  // < 50176
    const float4 v = *(const float4*)(x + (size_t)tok * C_ + lane * 4);
    float s = v.x + v.y + v.z + v.w;
    float q = v.x*v.x + v.y*v.y + v.z*v.z + v.w*v.w;
    for (int o = 32; o > 0; o >>= 1) { s += __shfl_xor(s, o, 64); q += __shfl_xor(q, o, 64); }
    float mu  = s * (1.0f / C_);
    float var = q * (1.0f / C_) - mu * mu;
    float rs  = rsqrtf(var + EPS_);
    float4 gg = *(const float4*)(g   + lane * 4);
    float4 bb = *(const float4*)(bta + lane * 4);
    float y0 = (v.x - mu) * rs * gg.x + bb.x;
    float y1 = (v.y - mu) * rs * gg.y + bb.y;
    float y2 = (v.z - mu) * rs * gg.z + bb.z;
    float y3 = (v.w - mu) * rs * gg.w + bb.w;
    size_t di;
    if (shifted) {
        int b = tok / 3136, p = tok % 3136;
        int ph = p / 56, pw = p % 56;
        int sh = ph - SS_; if (sh < 0) sh += HH;
        int sw = pw - SS_; if (sw < 0) sw += WWI;
        int bw = b * 64 + (sh / WS_) * 8 + (sw / WS_);
        int n  = (sh % WS_) * WS_ + (sw % WS_);
        di = ((size_t)bw * NN + n) * C_ + lane * 4;
    } else {
        di = (size_t)tok * C_ + lane * 4;
    }
    unsigned int lo = (unsigned int)f2bf(y0) | ((unsigned int)f2bf(y1) << 16);
    unsigned int hi = (unsigned int)f2bf(y2) | ((unsigned int)f2bf(y3) << 16);
    uint2 u; u.x = lo; u.y = hi;
    *(uint2*)(dst + di) = u;
}

// ---------------- MFMA GEMM, 128x128 tile, BK=32 ----------------
template<int EPI>
__global__ __launch_bounds__(256) void gemm_k(
    const unsigned short* __restrict__ A, const unsigned short* __restrict__ Bt,
    int K, const float* __restrict__ bias,
    const float* __restrict__ resid, float* __restrict__ outF,
    unsigned short* __restrict__ outQ, unsigned short* __restrict__ outK,
    unsigned short* __restrict__ outV)
{
    __shared__ unsigned short lA[128][40];  // pad 40 -> 80B row stride: 2-way, free
    __shared__ unsigned short lB[128][40];
    const int tid = threadIdx.x;
    const int m0 = blockIdx.y * 128, n0 = blockIdx.x * 128;
    const int wave = tid >> 6, lane = tid & 63, quad = lane >> 4, l16 = lane & 15;
    const int wm = wave >> 1, wn = wave & 1;
    const int srow = tid >> 1, scol = (tid & 1) * 16;

    f32x4 acc[4][4] = {};
    const int nk = K >> 5;
    for (int kk = 0; kk < nk; ++kk) {
        const int k0 = kk << 5;
        {
            size_t ga = (size_t)(m0 + srow) * K + k0 + scol;
            uint4 a0 = *(const uint4*)(A + ga);
            uint4 a1 = *(const uint4*)(A + ga + 8);
            size_t gb = (size_t)(n0 + srow) * K + k0 + scol;
            uint4 b0 = *(const uint4*)(Bt + gb);
            uint4 b1 = *(const uint4*)(Bt + gb + 8);
            *(uint4*)&lA[srow][scol]     = a0;
            *(uint4*)&lA[srow][scol + 8] = a1;
            *(uint4*)&lB[srow][scol]     = b0;
            *(uint4*)&lB[srow][scol + 8] = b1;
        }
        __syncthreads();
        bf16x8 af[4], bf[4];
        #pragma unroll
        for (int t = 0; t < 4; ++t) {
            af[t] = __builtin_bit_cast(bf16x8, *(const ushort8v*)&lA[wm * 64 + t * 16 + l16][quad * 8]);
            bf[t] = __builtin_bit_cast(bf16x8, *(const ushort8v*)&lB[wn * 64 + t * 16 + l16][quad * 8]);
        }
        #pragma unroll
        for (int mt = 0; mt < 4; ++mt)
            #pragma unroll
            for (int nt = 0; nt < 4; ++nt)
                acc[mt][nt] = __builtin_amdgcn_mfma_f32_16x16x32_bf16(af[mt], bf[nt], acc[mt][nt], 0, 0, 0);
        __syncthreads();
    }

    #pragma unroll
    for (int mt = 0; mt < 4; ++mt) {
        #pragma unroll
        for (int nt = 0; nt < 4; ++nt) {
            #pragma unroll
            for (int r = 0; r < 4; ++r) {
                int m = m0 + wm * 64 + mt * 16 + quad * 4 + r;
                int n = n0 + wn * 64 + nt * 16 + l16;
                float v = acc[mt][nt][r] + bias[n];
                if (EPI == 0) {            // QKV: scatter to q/k/v (bw, head, n, hd), q scaled
                    int c = n & 255;
                    int head = c >> 5, hd = c & 31;
                    int bw = m / NN, nw = m % NN;
                    size_t o = ((size_t)(bw * NH_ + head) * NN + nw) * HD_ + hd;
                    if      (n < 256) outQ[o] = f2bf(v * SCALE_);
                    else if (n < 512) outK[o] = f2bf(v);
                    else              outV[o] = f2bf(v);
                } else if (EPI == 1) {     // proj: window-reverse + unshift + residual -> x2 (d_out)
                    int bw = m / NN, nw = m % NN;
                    int b = bw >> 6, wi = bw & 63;
                    int sh = (wi >> 3) * WS_ + nw / WS_;
                    int sw = (wi & 7) * WS_ + nw % WS_;
                    int ph = sh + SS_; if (ph >= HH)  ph -= HH;
                    int pw = sw + SS_; if (pw >= WWI) pw -= WWI;
                    size_t t = ((size_t)b * 3136 + ph * 56 + pw) * C_ + n;
                    outF[t] = resid[t] + v;
                } else if (EPI == 2) {     // FC1 + exact GELU -> a1 bf16
                    float gl = 0.5f * v * (1.0f + erff(v * 0.70710678118654752f));
                    outQ[(size_t)m * 1024 + n] = f2bf(gl);
                } else {                   // FC2 + residual (d_out holds x2)
                    size_t t = (size_t)m * C_ + n;
                    outF[t] = outF[t] + v;
                }
            }
        }
    }
}

// ---------------- MFMA attention: one block per (window, head) ----------------
// 4 waves; wave w owns output rows [16w, 16w+16). 49 padded to 64.
__global__ __launch_bounds__(256) void attn_k(
    const unsigned short* __restrict__ qb, const unsigned short* __restrict__ kb,
    const unsigned short* __restrict__ vb, const unsigned short* __restrict__ cb,
    unsigned short* __restrict__ ob)
{
    __shared__ unsigned short qs[64][40];   // Q rows (pad 40: frag reads 2-way free)
    __shared__ unsigned short ks[64][40];   // K rows
    __shared__ unsigned short vt[32][72];   // V^T: [d][j], j padded to 64 (zeroed 49..63)
    __shared__ unsigned short sp[64][72];   // P bf16, A-layout rows
    __shared__ unsigned short cbs[2408];    // bias+mask slice
    const int tid = threadIdx.x;
    const int bw = blockIdx.x >> 3, head = blockIdx.x & 7;
    const size_t base = (size_t)blockIdx.x * (NN * HD_);   // (bw*8+head)*1568

    // ---- stage q,k rows / v transposed / cb slice ----
    for (int t = tid; t < 588; t += 256) {
        int seg = t / 196, idx = t - seg * 196;
        int e = idx * 8;                          // 8 shorts = 16B
        const unsigned short* src = (seg == 0 ? qb : seg == 1 ? kb : vb) + base + e;
        uint4 u = *(const uint4*)src;
        if (seg == 0)      *(uint4*)&qs[e >> 5][e & 31] = u;
        else if (seg == 1) *(uint4*)&ks[e >> 5][e & 31] = u;
        else {
            int n = e >> 5, hd = e & 31;
            const unsigned short* pu = (const unsigned short*)&u;
            #pragma unroll
            for (int uu = 0; uu < 8; ++uu) vt[hd + uu][n] = pu[uu];
        }
    }
    {
        const unsigned short* cbase = cb + (size_t)(((bw & 63) * 8 + head)) * 2408;
        for (int t = tid; t < 301; t += 256)
            *(uint4*)&cbs[t * 8] = *(const uint4*)(cbase + t * 8);
        for (int t = tid; t < 480; t += 256) vt[t / 15][NN + t % 15] = 0;  // zero j=49..63
    }
    __syncthreads();

    const int wave = tid >> 6, lane = tid & 63, quad = lane >> 4, l16 = lane & 15;
    const f32x4 zz = {};

    // ---- S = q·k^T via MFMA (K=32=HD) ----
    bf16x8 afq = __builtin_bit_cast(bf16x8, *(const ushort8v*)&qs[wave * 16 + l16][quad * 8]);
    f32x4 s4[4];
    #pragma unroll
    for (int jt = 0; jt < 4; ++jt) {
        bf16x8 bk = __builtin_bit_cast(bf16x8, *(const ushort8v*)&ks[jt * 16 + l16][quad * 8]);
        s4[jt] = __builtin_amdgcn_mfma_f32_16x16x32_bf16(afq, bk, zz, 0, 0, 0);
    }

    // ---- softmax per row (row i = wave*16 + quad*4 + r; cols across jt,l16) ----
    #pragma unroll
    for (int r = 0; r < 4; ++r) {
        int i = wave * 16 + quad * 4 + r;
        float vals[4];
        #pragma unroll
        for (int jt = 0; jt < 4; ++jt) {
            int j = jt * 16 + l16;
            vals[jt] = (i < NN && j < NN) ? s4[jt][r] + bf2f(cbs[i * NN + j]) : -1e30f;
        }
        float mx = fmaxf(fmaxf(vals[0], vals[1]), fmaxf(vals[2], vals[3]));
        #pragma unroll
        for (int o = 1; o < 16; o <<= 1) mx = fmaxf(mx, __shfl_xor(mx, o, 64));
        float e[4], sum = 0.0f;
        #pragma unroll
        for (int jt = 0; jt < 4; ++jt) { e[jt] = __expf(vals[jt] - mx); sum += e[jt]; }
        #pragma unroll
        for (int o = 1; o < 16; o <<= 1) sum += __shfl_xor(sum, o, 64);
        float inv = 1.0f / sum;
        #pragma unroll
        for (int jt = 0; jt < 4; ++jt) sp[i][jt * 16 + l16] = f2bf(e[jt] * inv);
    }
    __syncthreads();

    // ---- O = P·V via MFMA (K=64 over j, 2 chunks) ----
    bf16x8 ap[2];
    #pragma unroll
    for (int kt = 0; kt < 2; ++kt)
        ap[kt] = __builtin_bit_cast(bf16x8, *(const ushort8v*)&sp[wave * 16 + l16][kt * 32 + quad * 8]);
    f32x4 o4[2] = {};
    #pragma unroll
    for (int nt = 0; nt < 2; ++nt)
        #pragma unroll
        for (int kt = 0; kt < 2; ++kt) {
            bf16x8 bv = __builtin_bit_cast(bf16x8, *(const ushort8v*)&vt[nt * 16 + l16][kt * 32 + quad * 8]);
            o4[nt] = __builtin_amdgcn_mfma_f32_16x16x32_bf16(ap[kt], bv, o4[nt], 0, 0, 0);
        }
    #pragma unroll
    for (int nt = 0; nt < 2; ++nt)
        #pragma unroll
        for (int r = 0; r < 4; ++r) {
            int i = wave * 16 + quad * 4 + r;
            if (i < NN)
                ob[((size_t)bw * NN + i) * C_ + head * HD_ + nt * 16 + l16] = f2bf(o4[nt][r]);
        }
}

extern "C" void kernel_launch(void* const* d_in, const int* in_sizes, int n_in,
                              void* d_out, int out_size, void* d_ws, size_t ws_size,
                              hipStream_t stream)
{
    const float* x     = (const float*)d_in[0];
    const float* mask  = (const float*)d_in[1];
    const float* n1g   = (const float*)d_in[2];
    const float* n1b   = (const float*)d_in[3];
    const float* qkvw  = (const float*)d_in[4];
    const float* qkvb  = (const float*)d_in[5];
    const float* relb  = (const float*)d_in[6];
    const float* projw = (const float*)d_in[7];
    const float* projb = (const float*)d_in[8];
    const float* n2g   = (const float*)d_in[9];
    const float* n2b   = (const float*)d_in[10];
    const float* fc1w  = (const float*)d_in[11];
    const float* fc1b  = (const float*)d_in[12];
    const float* fc2w  = (const float*)d_in[13];
    const float* fc2b  = (const float*)d_in[14];
    float* out = (float*)d_out;

    unsigned short* wq = (unsigned short*)d_ws;   // all weights bf16, contiguous
    unsigned short* wp = wq + 196608;
    unsigned short* w1 = wq + 262144;
    unsigned short* w2 = wq + 524288;
    unsigned short* hw = wq + 786432;             // LN1-shift-partitioned (50176,256) bf16
    unsigned short* qb = hw + 12845056;           // (1024,8,49,32) bf16
    unsigned short* kb = qb + 12845056;
    unsigned short* vb = kb + 12845056;
    unsigned short* ob = vb + 12845056;           // attn out, windowed (50176,256) bf16
    unsigned short* h2 = ob + 12845056;           // LN2 out (50176,256) bf16
    unsigned short* a1 = h2 + 12845056;           // GELU(fc1) (50176,1024) bf16
    // cb aliases the head of a1: cb is consumed by attn_k, which completes
    // before gemm_k<2> (FC1) writes a1 on the same serial stream.
    unsigned short* cbt = a1;                     // (512, 2408) bf16 bias+mask table

    convw_k<<<3072, 256, 0, stream>>>(qkvw, projw, fc1w, fc2w, wq);
    cb_k<<<512, 256, 0, stream>>>(mask, relb, cbt);
    ln_k<<<12544, 256, 0, stream>>>(x, n1g, n1b, hw, 1);
    gemm_k<0><<<dim3(6, 392), 256, 0, stream>>>(hw, wq, 256, qkvb, nullptr, nullptr, qb, kb, vb);
    attn_k<<<8192, 256, 0, stream>>>(qb, kb, vb, cbt, ob);
    gemm_k<1><<<dim3(2, 392), 256, 0, stream>>>(ob, wp, 256, projb, x, out, nullptr, nullptr, nullptr);
    ln_k<<<12544, 256, 0, stream>>>(out, n2g, n2b, h2, 0);
    gemm_k<2><<<dim3(8, 392), 256, 0, stream>>>(h2, w1, 256, fc1b, nullptr, nullptr, a1, nullptr, nullptr);
    gemm_k<3><<<dim3(2, 392), 256, 0, stream>>>(a1, w2, 1024, fc2b, nullptr, out, nullptr, nullptr, nullptr);
}

// Round 3
// 429.383 us; speedup vs baseline: 1.2332x; 1.0317x over previous
//
#include <hip/hip_runtime.h>
#include <cmath>

#define B_    16
#define HH    56
#define WWI   56
#define C_    256
#define NH_   8
#define WS_   7
#define SS_   3
#define HD_   32
#define NTOK  50176          // B*56*56
#define NN    49             // window size squared
#define SCALE_ 0.17677669529663689f
#define EPS_  1e-5f

typedef __bf16  bf16x8  __attribute__((ext_vector_type(8)));
typedef float   f32x4   __attribute__((ext_vector_type(4)));
typedef unsigned short ushort8v __attribute__((ext_vector_type(8)));

__device__ __forceinline__ unsigned short f2bf(float f) {
    unsigned int u = __float_as_uint(f);
    unsigned int r = u + 0x7FFFu + ((u >> 16) & 1u);   // RNE
    return (unsigned short)(r >> 16);
}
__device__ __forceinline__ float bf2f(unsigned short h) {
    return __uint_as_float(((unsigned int)h) << 16);
}

// async global->LDS DMA, 16B per lane; deposits at wave-uniform lds base + lane*16
__device__ __forceinline__ void gload_lds16(const unsigned short* g, unsigned short* l) {
    __builtin_amdgcn_global_load_lds(
        (const __attribute__((address_space(1))) unsigned int*)g,
        (__attribute__((address_space(3))) unsigned int*)l, 16, 0, 0);
}

// ---------------- weight fp32 -> bf16 conversion ----------------
__global__ __launch_bounds__(256) void convw_k(
    const float* __restrict__ qkvw, const float* __restrict__ projw,
    const float* __restrict__ fc1w, const float* __restrict__ fc2w,
    unsigned short* __restrict__ dst)
{
    int i = blockIdx.x * 256 + threadIdx.x;          // < 786432
    float v;
    if      (i < 196608) v = qkvw[i];
    else if (i < 262144) v = projw[i - 196608];
    else if (i < 524288) v = fc1w[i - 262144];
    else                 v = fc2w[i - 524288];
    dst[i] = f2bf(v);
}

// ---------------- combined rel-bias + shift-mask table, bf16 ----------------
__global__ __launch_bounds__(256) void cb_k(
    const float* __restrict__ mask, const float* __restrict__ relb,
    unsigned short* __restrict__ cb)
{
    int s = blockIdx.x;                 // 512 slices = 64 windows * 8 heads
    int wi = s >> 3, head = s & 7;
    for (int p = threadIdx.x; p < 2408; p += 256) {
        float v = 0.0f;
        if (p < 2401) {
            int i = p / NN, j = p - i * NN;
            int di = i / 7 - j / 7 + 6, dj = i % 7 - j % 7 + 6;
            v = relb[(di * 13 + dj) * NH_ + head] + mask[(size_t)wi * 2401 + p];
        }
        cb[(size_t)s * 2408 + p] = f2bf(v);
    }
}

// ---------------- LayerNorm (+optional shift+window-partition) ----------------
__global__ __launch_bounds__(256) void ln_k(
    const float* __restrict__ x, const float* __restrict__ g,
    const float* __restrict__ bta, unsigned short* __restrict__ dst, int shifted)
{
    int wave = threadIdx.x >> 6, lane = threadIdx.x & 63;
    int tok = blockIdx.x * 4 + wave;                  // < 50176
    const float4 v = *(const float4*)(x + (size_t)tok * C_ + lane * 4);
    float s = v.x + v.y + v.z + v.w;
    float q = v.x*v.x + v.y*v.y + v.z*v.z + v.w*v.w;
    for (int o = 32; o > 0; o >>= 1) { s += __shfl_xor(s, o, 64); q += __shfl_xor(q, o, 64); }
    float mu  = s * (1.0f / C_);
    float var = q * (1.0f / C_) - mu * mu;
    float rs  = rsqrtf(var + EPS_);
    float4 gg = *(const float4*)(g   + lane * 4);
    float4 bb = *(const float4*)(bta + lane * 4);
    float y0 = (v.x - mu) * rs * gg.x + bb.x;
    float y1 = (v.y - mu) * rs * gg.y + bb.y;
    float y2 = (v.z - mu) * rs * gg.z + bb.z;
    float y3 = (v.w - mu) * rs * gg.w + bb.w;
    size_t di;
    if (shifted) {
        int b = tok / 3136, p = tok % 3136;
        int ph = p / 56, pw = p % 56;
        int sh = ph - SS_; if (sh < 0) sh += HH;
        int sw = pw - SS_; if (sw < 0) sw += WWI;
        int bw = b * 64 + (sh / WS_) * 8 + (sw / WS_);
        int n  = (sh % WS_) * WS_ + (sw % WS_);
        di = ((size_t)bw * NN + n) * C_ + lane * 4;
    } else {
        di = (size_t)tok * C_ + lane * 4;
    }
    unsigned int lo = (unsigned int)f2bf(y0) | ((unsigned int)f2bf(y1) << 16);
    unsigned int hi = (unsigned int)f2bf(y2) | ((unsigned int)f2bf(y3) << 16);
    uint2 u; u.x = lo; u.y = hi;
    *(uint2*)(dst + di) = u;
}

// ---------------- MFMA GEMM, 128x128 tile, BK=32, global_load_lds staging ----
template<int EPI>
__global__ __launch_bounds__(256) void gemm_k(
    const unsigned short* __restrict__ A, const unsigned short* __restrict__ Bt,
    int K, const float* __restrict__ bias,
    const float* __restrict__ resid, float* __restrict__ outF,
    unsigned short* __restrict__ outQ, unsigned short* __restrict__ outK,
    unsigned short* __restrict__ outV)
{
    // UNPADDED: global_load_lds deposits base+lane*16, padding would corrupt.
    // frag ds_read_b128 on 64B rows: 8 lanes per 4-bank group x 8 groups = all
    // 32 banks busy = 8clk/1024B = no-conflict floor.
    __shared__ unsigned short lA[128][32];
    __shared__ unsigned short lB[128][32];
    const int tid = threadIdx.x;
    const int m0 = blockIdx.y * 128, n0 = blockIdx.x * 128;
    const int wave = tid >> 6, lane = tid & 63, quad = lane >> 4, l16 = lane & 15;
    const int wm = wave >> 1, wn = wave & 1;
    const int r0 = tid >> 2, c0 = (tid & 3) * 8;   // staging row/col (shorts)
    unsigned short* lA0 = &lA[0][0] + wave * 512;  // wave-uniform DMA bases
    unsigned short* lA1 = lA0 + 2048;
    unsigned short* lB0 = &lB[0][0] + wave * 512;
    unsigned short* lB1 = lB0 + 2048;

    f32x4 acc[4][4] = {};
    const int nk = K >> 5;
    for (int kk = 0; kk < nk; ++kk) {
        const int k0 = kk << 5;
        gload_lds16(A  + (size_t)(m0 + r0)      * K + k0 + c0, lA0);
        gload_lds16(A  + (size_t)(m0 + r0 + 64) * K + k0 + c0, lA1);
        gload_lds16(Bt + (size_t)(n0 + r0)      * K + k0 + c0, lB0);
        gload_lds16(Bt + (size_t)(n0 + r0 + 64) * K + k0 + c0, lB1);
        __syncthreads();
        bf16x8 af[4], bfr[4];
        #pragma unroll
        for (int t = 0; t < 4; ++t) {
            af[t]  = __builtin_bit_cast(bf16x8, *(const ushort8v*)&lA[wm * 64 + t * 16 + l16][quad * 8]);
            bfr[t] = __builtin_bit_cast(bf16x8, *(const ushort8v*)&lB[wn * 64 + t * 16 + l16][quad * 8]);
        }
        #pragma unroll
        for (int mt = 0; mt < 4; ++mt)
            #pragma unroll
            for (int nt = 0; nt < 4; ++nt)
                acc[mt][nt] = __builtin_amdgcn_mfma_f32_16x16x32_bf16(af[mt], bfr[nt], acc[mt][nt], 0, 0, 0);
        __syncthreads();
    }

    #pragma unroll
    for (int mt = 0; mt < 4; ++mt) {
        #pragma unroll
        for (int nt = 0; nt < 4; ++nt) {
            #pragma unroll
            for (int r = 0; r < 4; ++r) {
                int m = m0 + wm * 64 + mt * 16 + quad * 4 + r;
                int n = n0 + wn * 64 + nt * 16 + l16;
                float v = acc[mt][nt][r] + bias[n];
                if (EPI == 0) {            // QKV: scatter to q/k/v (bw, head, n, hd), q scaled
                    int c = n & 255;
                    int head = c >> 5, hd = c & 31;
                    int bw = m / NN, nw = m % NN;
                    size_t o = ((size_t)(bw * NH_ + head) * NN + nw) * HD_ + hd;
                    if      (n < 256) outQ[o] = f2bf(v * SCALE_);
                    else if (n < 512) outK[o] = f2bf(v);
                    else              outV[o] = f2bf(v);
                } else if (EPI == 1) {     // proj: window-reverse + unshift + residual -> x2 (d_out)
                    int bw = m / NN, nw = m % NN;
                    int b = bw >> 6, wi = bw & 63;
                    int sh = (wi >> 3) * WS_ + nw / WS_;
                    int sw = (wi & 7) * WS_ + nw % WS_;
                    int ph = sh + SS_; if (ph >= HH)  ph -= HH;
                    int pw = sw + SS_; if (pw >= WWI) pw -= WWI;
                    size_t t = ((size_t)b * 3136 + ph * 56 + pw) * C_ + n;
                    outF[t] = resid[t] + v;
                } else if (EPI == 2) {     // FC1 + exact GELU -> a1 bf16
                    float gl = 0.5f * v * (1.0f + erff(v * 0.70710678118654752f));
                    outQ[(size_t)m * 1024 + n] = f2bf(gl);
                } else {                   // FC2 + residual (d_out holds x2)
                    size_t t = (size_t)m * C_ + n;
                    outF[t] = outF[t] + v;
                }
            }
        }
    }
}

// ---------------- MFMA attention: one block per (window, head) ----------------
__global__ __launch_bounds__(256) void attn_k(
    const unsigned short* __restrict__ qb, const unsigned short* __restrict__ kb,
    const unsigned short* __restrict__ vb, const unsigned short* __restrict__ cb,
    unsigned short* __restrict__ ob)
{
    __shared__ unsigned short qs[64][40];   // Q rows (pad 40: frag reads 2-way free)
    __shared__ unsigned short ks[64][40];   // K rows
    __shared__ unsigned short vt[32][72];   // V^T: [d][j], j padded to 64 (zeroed 49..63)
    __shared__ unsigned short sp[64][72];   // P bf16, A-layout rows
    __shared__ unsigned short cbs[2408];    // bias+mask slice
    const int tid = threadIdx.x;
    const int bw = blockIdx.x >> 3, head = blockIdx.x & 7;
    const size_t base = (size_t)blockIdx.x * (NN * HD_);   // (bw*8+head)*1568

    for (int t = tid; t < 588; t += 256) {
        int seg = t / 196, idx = t - seg * 196;
        int e = idx * 8;                          // 8 shorts = 16B
        const unsigned short* src = (seg == 0 ? qb : seg == 1 ? kb : vb) + base + e;
        uint4 u = *(const uint4*)src;
        if (seg == 0)      *(uint4*)&qs[e >> 5][e & 31] = u;
        else if (seg == 1) *(uint4*)&ks[e >> 5][e & 31] = u;
        else {
            int n = e >> 5, hd = e & 31;
            const unsigned short* pu = (const unsigned short*)&u;
            #pragma unroll
            for (int uu = 0; uu < 8; ++uu) vt[hd + uu][n] = pu[uu];
        }
    }
    {
        const unsigned short* cbase = cb + (size_t)(((bw & 63) * 8 + head)) * 2408;
        for (int t = tid; t < 301; t += 256)
            *(uint4*)&cbs[t * 8] = *(const uint4*)(cbase + t * 8);
        for (int t = tid; t < 480; t += 256) vt[t / 15][NN + t % 15] = 0;  // zero j=49..63
    }
    __syncthreads();

    const int wave = tid >> 6, lane = tid & 63, quad = lane >> 4, l16 = lane & 15;
    const f32x4 zz = {};

    bf16x8 afq = __builtin_bit_cast(bf16x8, *(const ushort8v*)&qs[wave * 16 + l16][quad * 8]);
    f32x4 s4[4];
    #pragma unroll
    for (int jt = 0; jt < 4; ++jt) {
        bf16x8 bk = __builtin_bit_cast(bf16x8, *(const ushort8v*)&ks[jt * 16 + l16][quad * 8]);
        s4[jt] = __builtin_amdgcn_mfma_f32_16x16x32_bf16(afq, bk, zz, 0, 0, 0);
    }

    #pragma unroll
    for (int r = 0; r < 4; ++r) {
        int i = wave * 16 + quad * 4 + r;
        float vals[4];
        #pragma unroll
        for (int jt = 0; jt < 4; ++jt) {
            int j = jt * 16 + l16;
            vals[jt] = (i < NN && j < NN) ? s4[jt][r] + bf2f(cbs[i * NN + j]) : -1e30f;
        }
        float mx = fmaxf(fmaxf(vals[0], vals[1]), fmaxf(vals[2], vals[3]));
        #pragma unroll
        for (int o = 1; o < 16; o <<= 1) mx = fmaxf(mx, __shfl_xor(mx, o, 64));
        float e[4], sum = 0.0f;
        #pragma unroll
        for (int jt = 0; jt < 4; ++jt) { e[jt] = __expf(vals[jt] - mx); sum += e[jt]; }
        #pragma unroll
        for (int o = 1; o < 16; o <<= 1) sum += __shfl_xor(sum, o, 64);
        float inv = 1.0f / sum;
        #pragma unroll
        for (int jt = 0; jt < 4; ++jt) sp[i][jt * 16 + l16] = f2bf(e[jt] * inv);
    }
    __syncthreads();

    bf16x8 ap[2];
    #pragma unroll
    for (int kt = 0; kt < 2; ++kt)
        ap[kt] = __builtin_bit_cast(bf16x8, *(const ushort8v*)&sp[wave * 16 + l16][kt * 32 + quad * 8]);
    f32x4 o4[2] = {};
    #pragma unroll
    for (int nt = 0; nt < 2; ++nt)
        #pragma unroll
        for (int kt = 0; kt < 2; ++kt) {
            bf16x8 bv = __builtin_bit_cast(bf16x8, *(const ushort8v*)&vt[nt * 16 + l16][kt * 32 + quad * 8]);
            o4[nt] = __builtin_amdgcn_mfma_f32_16x16x32_bf16(ap[kt], bv, o4[nt], 0, 0, 0);
        }
    #pragma unroll
    for (int nt = 0; nt < 2; ++nt)
        #pragma unroll
        for (int r = 0; r < 4; ++r) {
            int i = wave * 16 + quad * 4 + r;
            if (i < NN)
                ob[((size_t)bw * NN + i) * C_ + head * HD_ + nt * 16 + l16] = f2bf(o4[nt][r]);
        }
}

extern "C" void kernel_launch(void* const* d_in, const int* in_sizes, int n_in,
                              void* d_out, int out_size, void* d_ws, size_t ws_size,
                              hipStream_t stream)
{
    const float* x     = (const float*)d_in[0];
    const float* mask  = (const float*)d_in[1];
    const float* n1g   = (const float*)d_in[2];
    const float* n1b   = (const float*)d_in[3];
    const float* qkvw  = (const float*)d_in[4];
    const float* qkvb  = (const float*)d_in[5];
    const float* relb  = (const float*)d_in[6];
    const float* projw = (const float*)d_in[7];
    const float* projb = (const float*)d_in[8];
    const float* n2g   = (const float*)d_in[9];
    const float* n2b   = (const float*)d_in[10];
    const float* fc1w  = (const float*)d_in[11];
    const float* fc1b  = (const float*)d_in[12];
    const float* fc2w  = (const float*)d_in[13];
    const float* fc2b  = (const float*)d_in[14];
    float* out = (float*)d_out;

    unsigned short* wq = (unsigned short*)d_ws;   // all weights bf16, contiguous
    unsigned short* wp = wq + 196608;
    unsigned short* w1 = wq + 262144;
    unsigned short* w2 = wq + 524288;
    unsigned short* hw = wq + 786432;             // LN1-shift-partitioned (50176,256) bf16
    unsigned short* qb = hw + 12845056;           // (1024,8,49,32) bf16
    unsigned short* kb = qb + 12845056;
    unsigned short* vb = kb + 12845056;
    unsigned short* ob = vb + 12845056;           // attn out, windowed (50176,256) bf16
    unsigned short* h2 = ob + 12845056;           // LN2 out (50176,256) bf16
    unsigned short* a1 = h2 + 12845056;           // GELU(fc1) (50176,1024) bf16
    unsigned short* cbt = a1;                     // cb aliases a1 (attn_k finishes before FC1 writes a1)

    convw_k<<<3072, 256, 0, stream>>>(qkvw, projw, fc1w, fc2w, wq);
    cb_k<<<512, 256, 0, stream>>>(mask, relb, cbt);
    ln_k<<<12544, 256, 0, stream>>>(x, n1g, n1b, hw, 1);
    gemm_k<0><<<dim3(6, 392), 256, 0, stream>>>(hw, wq, 256, qkvb, nullptr, nullptr, qb, kb, vb);
    attn_k<<<8192, 256, 0, stream>>>(qb, kb, vb, cbt, ob);
    gemm_k<1><<<dim3(2, 392), 256, 0, stream>>>(ob, wp, 256, projb, x, out, nullptr, nullptr, nullptr);
    ln_k<<<12544, 256, 0, stream>>>(out, n2g, n2b, h2, 0);
    gemm_k<2><<<dim3(8, 392), 256, 0, stream>>>(h2, w1, 256, fc1b, nullptr, nullptr, a1, nullptr, nullptr);
    gemm_k<3><<<dim3(2, 392), 256, 0, stream>>>(a1, w2, 1024, fc2b, nullptr, out, nullptr, nullptr, nullptr);
}

// Round 4
// 415.371 us; speedup vs baseline: 1.2748x; 1.0337x over previous
//
#include <hip/hip_runtime.h>
#include <cmath>

#define B_    16
#define HH    56
#define WWI   56
#define C_    256
#define NH_   8
#define WS_   7
#define SS_   3
#define HD_   32
#define NTOK  50176          // B*56*56
#define NN    49             // window size squared
#define SCALE_ 0.17677669529663689f
#define EPS_  1e-5f

typedef __bf16  bf16x8  __attribute__((ext_vector_type(8)));
typedef float   f32x4   __attribute__((ext_vector_type(4)));
typedef unsigned short ushort8v __attribute__((ext_vector_type(8)));

__device__ __forceinline__ unsigned short f2bf(float f) {
    unsigned int u = __float_as_uint(f);
    unsigned int r = u + 0x7FFFu + ((u >> 16) & 1u);   // RNE
    return (unsigned short)(r >> 16);
}
__device__ __forceinline__ float bf2f(unsigned short h) {
    return __uint_as_float(((unsigned int)h) << 16);
}
// tanh-form GELU: |err| <= ~3e-3 vs exact erf form; hw v_exp_f32 + rcp
__device__ __forceinline__ float gelu_t(float x) {
    float t = 0.7978845608028654f * (x + 0.044715f * x * x * x);
    float e = __expf(2.0f * t);
    float th = 1.0f - 2.0f * __builtin_amdgcn_rcpf(e + 1.0f);
    return 0.5f * x * (1.0f + th);
}

// async global->LDS DMA, 16B per lane; deposits at wave-uniform lds base + lane*16
__device__ __forceinline__ void gload_lds16(const unsigned short* g, unsigned short* l) {
    __builtin_amdgcn_global_load_lds(
        (const __attribute__((address_space(1))) unsigned int*)g,
        (__attribute__((address_space(3))) unsigned int*)l, 16, 0, 0);
}

// ---------------- weight fp32 -> bf16 conversion ----------------
__global__ __launch_bounds__(256) void convw_k(
    const float* __restrict__ qkvw, const float* __restrict__ projw,
    const float* __restrict__ fc1w, const float* __restrict__ fc2w,
    unsigned short* __restrict__ dst)
{
    int i = blockIdx.x * 256 + threadIdx.x;          // < 786432
    float v;
    if      (i < 196608) v = qkvw[i];
    else if (i < 262144) v = projw[i - 196608];
    else if (i < 524288) v = fc1w[i - 262144];
    else                 v = fc2w[i - 524288];
    dst[i] = f2bf(v);
}

// ---------------- combined rel-bias + shift-mask table, bf16 ----------------
__global__ __launch_bounds__(256) void cb_k(
    const float* __restrict__ mask, const float* __restrict__ relb,
    unsigned short* __restrict__ cb)
{
    int s = blockIdx.x;                 // 512 slices = 64 windows * 8 heads
    int wi = s >> 3, head = s & 7;
    for (int p = threadIdx.x; p < 2408; p += 256) {
        float v = 0.0f;
        if (p < 2401) {
            int i = p / NN, j = p - i * NN;
            int di = i / 7 - j / 7 + 6, dj = i % 7 - j % 7 + 6;
            v = relb[(di * 13 + dj) * NH_ + head] + mask[(size_t)wi * 2401 + p];
        }
        cb[(size_t)s * 2408 + p] = f2bf(v);
    }
}

// ---------------- LayerNorm (+optional shift+window-partition) ----------------
__global__ __launch_bounds__(256) void ln_k(
    const float* __restrict__ x, const float* __restrict__ g,
    const float* __restrict__ bta, unsigned short* __restrict__ dst, int shifted)
{
    int wave = threadIdx.x >> 6, lane = threadIdx.x & 63;
    int tok = blockIdx.x * 4 + wave;                  // < 50176
    const float4 v = *(const float4*)(x + (size_t)tok * C_ + lane * 4);
    float s = v.x + v.y + v.z + v.w;
    float q = v.x*v.x + v.y*v.y + v.z*v.z + v.w*v.w;
    for (int o = 32; o > 0; o >>= 1) { s += __shfl_xor(s, o, 64); q += __shfl_xor(q, o, 64); }
    float mu  = s * (1.0f / C_);
    float var = q * (1.0f / C_) - mu * mu;
    float rs  = rsqrtf(var + EPS_);
    float4 gg = *(const float4*)(g   + lane * 4);
    float4 bb = *(const float4*)(bta + lane * 4);
    float y0 = (v.x - mu) * rs * gg.x + bb.x;
    float y1 = (v.y - mu) * rs * gg.y + bb.y;
    float y2 = (v.z - mu) * rs * gg.z + bb.z;
    float y3 = (v.w - mu) * rs * gg.w + bb.w;
    size_t di;
    if (shifted) {
        int b = tok / 3136, p = tok % 3136;
        int ph = p / 56, pw = p % 56;
        int sh = ph - SS_; if (sh < 0) sh += HH;
        int sw = pw - SS_; if (sw < 0) sw += WWI;
        int bw = b * 64 + (sh / WS_) * 8 + (sw / WS_);
        int n  = (sh % WS_) * WS_ + (sw % WS_);
        di = ((size_t)bw * NN + n) * C_ + lane * 4;
    } else {
        di = (size_t)tok * C_ + lane * 4;
    }
    unsigned int lo = (unsigned int)f2bf(y0) | ((unsigned int)f2bf(y1) << 16);
    unsigned int hi = (unsigned int)f2bf(y2) | ((unsigned int)f2bf(y3) << 16);
    uint2 u; u.x = lo; u.y = hi;
    *(uint2*)(dst + di) = u;
}

// ---------------- MFMA GEMM, 128x128 tile, BK=32, DMA staging, bounce epilogue
template<int EPI>
__global__ __launch_bounds__(256) void gemm_k(
    const unsigned short* __restrict__ A, const unsigned short* __restrict__ Bt,
    int K, const float* __restrict__ bias,
    const float* __restrict__ resid, float* __restrict__ outF,
    unsigned short* __restrict__ outQ, unsigned short* __restrict__ outK,
    unsigned short* __restrict__ outV)
{
    // smem overlay: K-loop staging (lA/lB, unpadded for DMA) then epilogue bounce
    __shared__ __align__(16) unsigned char smem[34816];
    unsigned short* sA = (unsigned short*)smem;          // [128][32]
    unsigned short* sB = (unsigned short*)(smem + 8192); // [128][32]
    const int tid = threadIdx.x;
    const int m0 = blockIdx.y * 128, n0 = blockIdx.x * 128;
    const int wave = tid >> 6, lane = tid & 63, quad = lane >> 4, l16 = lane & 15;
    const int wm = wave >> 1, wn = wave & 1;
    const int r0 = tid >> 2, c0 = (tid & 3) * 8;   // staging row/col (shorts)
    unsigned short* lA0 = sA + wave * 512;         // wave-uniform DMA bases
    unsigned short* lA1 = lA0 + 2048;
    unsigned short* lB0 = sB + wave * 512;
    unsigned short* lB1 = lB0 + 2048;

    f32x4 acc[4][4] = {};
    const int nk = K >> 5;
    for (int kk = 0; kk < nk; ++kk) {
        const int k0 = kk << 5;
        gload_lds16(A  + (size_t)(m0 + r0)      * K + k0 + c0, lA0);
        gload_lds16(A  + (size_t)(m0 + r0 + 64) * K + k0 + c0, lA1);
        gload_lds16(Bt + (size_t)(n0 + r0)      * K + k0 + c0, lB0);
        gload_lds16(Bt + (size_t)(n0 + r0 + 64) * K + k0 + c0, lB1);
        __syncthreads();
        bf16x8 af[4], bfr[4];
        #pragma unroll
        for (int t = 0; t < 4; ++t) {
            af[t]  = __builtin_bit_cast(bf16x8, *(const ushort8v*)(sA + (wm * 64 + t * 16 + l16) * 32 + quad * 8));
            bfr[t] = __builtin_bit_cast(bf16x8, *(const ushort8v*)(sB + (wn * 64 + t * 16 + l16) * 32 + quad * 8));
        }
        #pragma unroll
        for (int mt = 0; mt < 4; ++mt)
            #pragma unroll
            for (int nt = 0; nt < 4; ++nt)
                acc[mt][nt] = __builtin_amdgcn_mfma_f32_16x16x32_bf16(af[mt], bfr[nt], acc[mt][nt], 0, 0, 0);
        __syncthreads();
    }

    float b4[4];
    #pragma unroll
    for (int nt = 0; nt < 4; ++nt) b4[nt] = bias[n0 + wn * 64 + nt * 16 + l16];

    if (EPI == 0 || EPI == 2) {
        // ---- bf16 output: bounce to LDS, store packed uint4 ----
        unsigned short (*swB)[136] = (unsigned short (*)[136])smem;  // 128x136x2 = 34816B
        const int seg = n0 >> 8;                      // EPI0: 0=q 1=k 2=v (block never straddles)
        const float qs = (EPI == 0 && seg == 0) ? SCALE_ : 1.0f;
        #pragma unroll
        for (int mt = 0; mt < 4; ++mt)
            #pragma unroll
            for (int nt = 0; nt < 4; ++nt)
                #pragma unroll
                for (int r = 0; r < 4; ++r) {
                    float v = acc[mt][nt][r] + b4[nt];
                    if (EPI == 0) v *= qs; else v = gelu_t(v);
                    swB[wm * 64 + mt * 16 + quad * 4 + r][wn * 64 + nt * 16 + l16] = f2bf(v);
                }
        __syncthreads();
        if (EPI == 0) {
            unsigned short* dstp = seg == 0 ? outQ : (seg == 1 ? outK : outV);
            const int nbase = n0 & 255;
            for (int t = tid; t < 2048; t += 256) {
                int row = t >> 4, c8 = (t & 15) * 8;
                int m = m0 + row, bw = m / NN, nw = m - bw * NN;
                int cc = nbase + c8;
                uint4 u = *(uint4*)&swB[row][c8];
                *(uint4*)&dstp[(((size_t)bw * NH_ + (cc >> 5)) * NN + nw) * HD_ + (cc & 31)] = u;
            }
        } else {
            for (int t = tid; t < 2048; t += 256) {
                int row = t >> 4, c8 = (t & 15) * 8;
                uint4 u = *(uint4*)&swB[row][c8];
                *(uint4*)&outQ[(size_t)(m0 + row) * 1024 + n0 + c8] = u;
            }
        }
    } else {
        // ---- fp32 output: two 64-row passes through LDS, float4 stores ----
        float (*swF)[132] = (float (*)[132])smem;     // 64x132x4 = 33792B
        #pragma unroll
        for (int p = 0; p < 2; ++p) {
            __syncthreads();
            if (wm == p) {
                #pragma unroll
                for (int mt = 0; mt < 4; ++mt)
                    #pragma unroll
                    for (int nt = 0; nt < 4; ++nt)
                        #pragma unroll
                        for (int r = 0; r < 4; ++r)
                            swF[mt * 16 + quad * 4 + r][wn * 64 + nt * 16 + l16] = acc[mt][nt][r] + b4[nt];
            }
            __syncthreads();
            for (int t = tid; t < 2048; t += 256) {
                int rl = t >> 5, c4 = (t & 31) * 4;
                size_t tt;
                if (EPI == 1) {                       // window-reverse + unshift
                    int m = m0 + p * 64 + rl, bw = m / NN, nw = m - bw * NN;
                    int b = bw >> 6, wi = bw & 63;
                    int sh = (wi >> 3) * WS_ + nw / WS_;
                    int sw = (wi & 7) * WS_ + nw % WS_;
                    int ph = sh + SS_; if (ph >= HH)  ph -= HH;
                    int pw = sw + SS_; if (pw >= WWI) pw -= WWI;
                    tt = ((size_t)b * 3136 + ph * 56 + pw) * C_ + n0 + c4;
                } else {
                    tt = (size_t)(m0 + p * 64 + rl) * C_ + n0 + c4;
                }
                float4 u = *(float4*)&swF[rl][c4];
                const float4 rr = (EPI == 1) ? *(const float4*)&resid[tt]
                                             : *(const float4*)&outF[tt];
                u.x += rr.x; u.y += rr.y; u.z += rr.z; u.w += rr.w;
                *(float4*)&outF[tt] = u;
            }
        }
    }
}

// ---------------- MFMA attention: one block per (window, head) ----------------
__global__ __launch_bounds__(256) void attn_k(
    const unsigned short* __restrict__ qb, const unsigned short* __restrict__ kb,
    const unsigned short* __restrict__ vb, const unsigned short* __restrict__ cb,
    unsigned short* __restrict__ ob)
{
    __shared__ unsigned short qs[64][40];   // Q rows (pad 40: frag reads 2-way free)
    __shared__ unsigned short ks[64][40];   // K rows
    __shared__ unsigned short vt[32][72];   // V^T: [d][j], j padded to 64 (zeroed 49..63)
    __shared__ unsigned short sp[64][72];   // P bf16, A-layout rows
    __shared__ unsigned short cbs[2408];    // bias+mask slice
    const int tid = threadIdx.x;
    const int bw = blockIdx.x >> 3, head = blockIdx.x & 7;
    const size_t base = (size_t)blockIdx.x * (NN * HD_);   // (bw*8+head)*1568

    for (int t = tid; t < 588; t += 256) {
        int seg = t / 196, idx = t - seg * 196;
        int e = idx * 8;                          // 8 shorts = 16B
        const unsigned short* src = (seg == 0 ? qb : seg == 1 ? kb : vb) + base + e;
        uint4 u = *(const uint4*)src;
        if (seg == 0)      *(uint4*)&qs[e >> 5][e & 31] = u;
        else if (seg == 1) *(uint4*)&ks[e >> 5][e & 31] = u;
        else {
            int n = e >> 5, hd = e & 31;
            const unsigned short* pu = (const unsigned short*)&u;
            #pragma unroll
            for (int uu = 0; uu < 8; ++uu) vt[hd + uu][n] = pu[uu];
        }
    }
    {
        const unsigned short* cbase = cb + (size_t)(((bw & 63) * 8 + head)) * 2408;
        for (int t = tid; t < 301; t += 256)
            *(uint4*)&cbs[t * 8] = *(const uint4*)(cbase + t * 8);
        for (int t = tid; t < 480; t += 256) vt[t / 15][NN + t % 15] = 0;  // zero j=49..63
    }
    __syncthreads();

    const int wave = tid >> 6, lane = tid & 63, quad = lane >> 4, l16 = lane & 15;
    const f32x4 zz = {};

    bf16x8 afq = __builtin_bit_cast(bf16x8, *(const ushort8v*)&qs[wave * 16 + l16][quad * 8]);
    f32x4 s4[4];
    #pragma unroll
    for (int jt = 0; jt < 4; ++jt) {
        bf16x8 bk = __builtin_bit_cast(bf16x8, *(const ushort8v*)&ks[jt * 16 + l16][quad * 8]);
        s4[jt] = __builtin_amdgcn_mfma_f32_16x16x32_bf16(afq, bk, zz, 0, 0, 0);
    }

    #pragma unroll
    for (int r = 0; r < 4; ++r) {
        int i = wave * 16 + quad * 4 + r;
        float vals[4];
        #pragma unroll
        for (int jt = 0; jt < 4; ++jt) {
            int j = jt * 16 + l16;
            vals[jt] = (i < NN && j < NN) ? s4[jt][r] + bf2f(cbs[i * NN + j]) : -1e30f;
        }
        float mx = fmaxf(fmaxf(vals[0], vals[1]), fmaxf(vals[2], vals[3]));
        #pragma unroll
        for (int o = 1; o < 16; o <<= 1) mx = fmaxf(mx, __shfl_xor(mx, o, 64));
        float e[4], sum = 0.0f;
        #pragma unroll
        for (int jt = 0; jt < 4; ++jt) { e[jt] = __expf(vals[jt] - mx); sum += e[jt]; }
        #pragma unroll
        for (int o = 1; o < 16; o <<= 1) sum += __shfl_xor(sum, o, 64);
        float inv = 1.0f / sum;
        #pragma unroll
        for (int jt = 0; jt < 4; ++jt) sp[i][jt * 16 + l16] = f2bf(e[jt] * inv);
    }
    __syncthreads();

    bf16x8 ap[2];
    #pragma unroll
    for (int kt = 0; kt < 2; ++kt)
        ap[kt] = __builtin_bit_cast(bf16x8, *(const ushort8v*)&sp[wave * 16 + l16][kt * 32 + quad * 8]);
    f32x4 o4[2] = {};
    #pragma unroll
    for (int nt = 0; nt < 2; ++nt)
        #pragma unroll
        for (int kt = 0; kt < 2; ++kt) {
            bf16x8 bv = __builtin_bit_cast(bf16x8, *(const ushort8v*)&vt[nt * 16 + l16][kt * 32 + quad * 8]);
            o4[nt] = __builtin_amdgcn_mfma_f32_16x16x32_bf16(ap[kt], bv, o4[nt], 0, 0, 0);
        }
    #pragma unroll
    for (int nt = 0; nt < 2; ++nt)
        #pragma unroll
        for (int r = 0; r < 4; ++r) {
            int i = wave * 16 + quad * 4 + r;
            if (i < NN)
                ob[((size_t)bw * NN + i) * C_ + head * HD_ + nt * 16 + l16] = f2bf(o4[nt][r]);
        }
}

extern "C" void kernel_launch(void* const* d_in, const int* in_sizes, int n_in,
                              void* d_out, int out_size, void* d_ws, size_t ws_size,
                              hipStream_t stream)
{
    const float* x     = (const float*)d_in[0];
    const float* mask  = (const float*)d_in[1];
    const float* n1g   = (const float*)d_in[2];
    const float* n1b   = (const float*)d_in[3];
    const float* qkvw  = (const float*)d_in[4];
    const float* qkvb  = (const float*)d_in[5];
    const float* relb  = (const float*)d_in[6];
    const float* projw = (const float*)d_in[7];
    const float* projb = (const float*)d_in[8];
    const float* n2g   = (const float*)d_in[9];
    const float* n2b   = (const float*)d_in[10];
    const float* fc1w  = (const float*)d_in[11];
    const float* fc1b  = (const float*)d_in[12];
    const float* fc2w  = (const float*)d_in[13];
    const float* fc2b  = (const float*)d_in[14];
    float* out = (float*)d_out;

    unsigned short* wq = (unsigned short*)d_ws;   // all weights bf16, contiguous
    unsigned short* wp = wq + 196608;
    unsigned short* w1 = wq + 262144;
    unsigned short* w2 = wq + 524288;
    unsigned short* hw = wq + 786432;             // LN1-shift-partitioned (50176,256) bf16
    unsigned short* qb = hw + 12845056;           // (1024,8,49,32) bf16
    unsigned short* kb = qb + 12845056;
    unsigned short* vb = kb + 12845056;
    unsigned short* ob = vb + 12845056;           // attn out, windowed (50176,256) bf16
    unsigned short* h2 = ob + 12845056;           // LN2 out (50176,256) bf16
    unsigned short* a1 = h2 + 12845056;           // GELU(fc1) (50176,1024) bf16
    unsigned short* cbt = a1;                     // cb aliases a1 (attn_k finishes before FC1 writes a1)

    convw_k<<<3072, 256, 0, stream>>>(qkvw, projw, fc1w, fc2w, wq);
    cb_k<<<512, 256, 0, stream>>>(mask, relb, cbt);
    ln_k<<<12544, 256, 0, stream>>>(x, n1g, n1b, hw, 1);
    gemm_k<0><<<dim3(6, 392), 256, 0, stream>>>(hw, wq, 256, qkvb, nullptr, nullptr, qb, kb, vb);
    attn_k<<<8192, 256, 0, stream>>>(qb, kb, vb, cbt, ob);
    gemm_k<1><<<dim3(2, 392), 256, 0, stream>>>(ob, wp, 256, projb, x, out, nullptr, nullptr, nullptr);
    ln_k<<<12544, 256, 0, stream>>>(out, n2g, n2b, h2, 0);
    gemm_k<2><<<dim3(8, 392), 256, 0, stream>>>(h2, w1, 256, fc1b, nullptr, nullptr, a1, nullptr, nullptr);
    gemm_k<3><<<dim3(2, 392), 256, 0, stream>>>(a1, w2, 1024, fc2b, nullptr, out, nullptr, nullptr, nullptr);
}

// Round 5
// 375.624 us; speedup vs baseline: 1.4096x; 1.1058x over previous
//
#include <hip/hip_runtime.h>
#include <cmath>

#define B_    16
#define HH    56
#define WWI   56
#define C_    256
#define NH_   8
#define WS_   7
#define SS_   3
#define HD_   32
#define NTOK  50176          // B*56*56
#define NN    49             // window size squared
#define SCALE_ 0.17677669529663689f
#define EPS_  1e-5f

typedef __bf16  bf16x8  __attribute__((ext_vector_type(8)));
typedef float   f32x4   __attribute__((ext_vector_type(4)));
typedef unsigned short ushort8v __attribute__((ext_vector_type(8)));

__device__ __forceinline__ unsigned short f2bf(float f) {
    unsigned int u = __float_as_uint(f);
    unsigned int r = u + 0x7FFFu + ((u >> 16) & 1u);   // RNE
    return (unsigned short)(r >> 16);
}
__device__ __forceinline__ float bf2f(unsigned short h) {
    return __uint_as_float(((unsigned int)h) << 16);
}
// tanh-form GELU: |err| <= ~3e-3 vs exact erf form; hw v_exp_f32 + rcp
__device__ __forceinline__ float gelu_t(float x) {
    float t = 0.7978845608028654f * (x + 0.044715f * x * x * x);
    float e = __expf(2.0f * t);
    float th = 1.0f - 2.0f * __builtin_amdgcn_rcpf(e + 1.0f);
    return 0.5f * x * (1.0f + th);
}

// async global->LDS DMA, 16B per lane; deposits at wave-uniform lds base + lane*16
__device__ __forceinline__ void gload_lds16(const unsigned short* g, unsigned short* l) {
    __builtin_amdgcn_global_load_lds(
        (const __attribute__((address_space(1))) unsigned int*)g,
        (__attribute__((address_space(3))) unsigned int*)l, 16, 0, 0);
}

// ---------------- weight fp32 -> bf16 conversion ----------------
__global__ __launch_bounds__(256) void convw_k(
    const float* __restrict__ qkvw, const float* __restrict__ projw,
    const float* __restrict__ fc1w, const float* __restrict__ fc2w,
    unsigned short* __restrict__ dst)
{
    int i = blockIdx.x * 256 + threadIdx.x;          // < 786432
    float v;
    if      (i < 196608) v = qkvw[i];
    else if (i < 262144) v = projw[i - 196608];
    else if (i < 524288) v = fc1w[i - 262144];
    else                 v = fc2w[i - 524288];
    dst[i] = f2bf(v);
}

// ---------------- combined rel-bias + shift-mask table, bf16 ----------------
__global__ __launch_bounds__(256) void cb_k(
    const float* __restrict__ mask, const float* __restrict__ relb,
    unsigned short* __restrict__ cb)
{
    int s = blockIdx.x;                 // 512 slices = 64 windows * 8 heads
    int wi = s >> 3, head = s & 7;
    for (int p = threadIdx.x; p < 2408; p += 256) {
        float v = 0.0f;
        if (p < 2401) {
            int i = p / NN, j = p - i * NN;
            int di = i / 7 - j / 7 + 6, dj = i % 7 - j % 7 + 6;
            v = relb[(di * 13 + dj) * NH_ + head] + mask[(size_t)wi * 2401 + p];
        }
        cb[(size_t)s * 2408 + p] = f2bf(v);
    }
}

// ---------------- LayerNorm (+optional shift+window-partition) ----------------
__global__ __launch_bounds__(256) void ln_k(
    const float* __restrict__ x, const float* __restrict__ g,
    const float* __restrict__ bta, unsigned short* __restrict__ dst, int shifted)
{
    int wave = threadIdx.x >> 6, lane = threadIdx.x & 63;
    int tok = blockIdx.x * 4 + wave;                  // < 50176
    const float4 v = *(const float4*)(x + (size_t)tok * C_ + lane * 4);
    float s = v.x + v.y + v.z + v.w;
    float q = v.x*v.x + v.y*v.y + v.z*v.z + v.w*v.w;
    for (int o = 32; o > 0; o >>= 1) { s += __shfl_xor(s, o, 64); q += __shfl_xor(q, o, 64); }
    float mu  = s * (1.0f / C_);
    float var = q * (1.0f / C_) - mu * mu;
    float rs  = rsqrtf(var + EPS_);
    float4 gg = *(const float4*)(g   + lane * 4);
    float4 bb = *(const float4*)(bta + lane * 4);
    float y0 = (v.x - mu) * rs * gg.x + bb.x;
    float y1 = (v.y - mu) * rs * gg.y + bb.y;
    float y2 = (v.z - mu) * rs * gg.z + bb.z;
    float y3 = (v.w - mu) * rs * gg.w + bb.w;
    size_t di;
    if (shifted) {
        int b = tok / 3136, p = tok % 3136;
        int ph = p / 56, pw = p % 56;
        int sh = ph - SS_; if (sh < 0) sh += HH;
        int sw = pw - SS_; if (sw < 0) sw += WWI;
        int bw = b * 64 + (sh / WS_) * 8 + (sw / WS_);
        int n  = (sh % WS_) * WS_ + (sw % WS_);
        di = ((size_t)bw * NN + n) * C_ + lane * 4;
    } else {
        di = (size_t)tok * C_ + lane * 4;
    }
    unsigned int lo = (unsigned int)f2bf(y0) | ((unsigned int)f2bf(y1) << 16);
    unsigned int hi = (unsigned int)f2bf(y2) | ((unsigned int)f2bf(y3) << 16);
    uint2 u; u.x = lo; u.y = hi;
    *(uint2*)(dst + di) = u;
}

// ---------------- MFMA GEMM, 128x128 tile, BK=32, pipelined DMA staging ------
// XCD-locality swizzle: 1-D grid of 392*NT blocks; xcd = lin&7 owns m-tiles
// [xcd*49, xcd*49+49), walked n-fastest so A-strips are fetched ~once per chip.
template<int EPI, int NT>
__global__ __launch_bounds__(256) void gemm_k(
    const unsigned short* __restrict__ A, const unsigned short* __restrict__ Bt,
    int K, const float* __restrict__ bias,
    const float* __restrict__ resid, float* __restrict__ outF,
    unsigned short* __restrict__ outQ, unsigned short* __restrict__ outK,
    unsigned short* __restrict__ outV)
{
    // smem overlay: 2x double-buffered staging (4x8KB) then epilogue bounce
    __shared__ __align__(16) unsigned char smem[34816];
    const int tid = threadIdx.x;
    const int lin = blockIdx.x;
    const int xcd = lin & 7, t = lin >> 3;
    const int m0 = (xcd * 49 + t / NT) * 128;
    const int n0 = (t % NT) * 128;
    const int wave = tid >> 6, lane = tid & 63, quad = lane >> 4, l16 = lane & 15;
    const int wm = wave >> 1, wn = wave & 1;
    const int r0 = tid >> 2, c0 = (tid & 3) * 8;   // staging row/col (shorts)

    const size_t gA0 = (size_t)(m0 + r0) * K + c0;
    const size_t gA1 = (size_t)(m0 + r0 + 64) * K + c0;
    const size_t gB0 = (size_t)(n0 + r0) * K + c0;
    const size_t gB1 = (size_t)(n0 + r0 + 64) * K + c0;
    const int woff = wave * 512;

    f32x4 acc[4][4] = {};
    const int nk = K >> 5;
    // pre-issue tile 0 into buffer 0
    {
        unsigned short* sA = (unsigned short*)smem;
        unsigned short* sB = sA + 4096;
        gload_lds16(A + gA0, sA + woff);
        gload_lds16(A + gA1, sA + woff + 2048);
        gload_lds16(Bt + gB0, sB + woff);
        gload_lds16(Bt + gB1, sB + woff + 2048);
    }
    for (int kk = 0; kk < nk; ++kk) {
        if (kk + 1 < nk) {                      // prefetch next tile, other buffer
            const int k1 = (kk + 1) << 5;
            unsigned short* sA = (unsigned short*)(smem + ((kk + 1) & 1) * 16384);
            unsigned short* sB = sA + 4096;
            gload_lds16(A + gA0 + k1, sA + woff);
            gload_lds16(A + gA1 + k1, sA + woff + 2048);
            gload_lds16(Bt + gB0 + k1, sB + woff);
            gload_lds16(Bt + gB1 + k1, sB + woff + 2048);
            __asm volatile("s_waitcnt vmcnt(4)\n\ts_barrier" ::: "memory");
        } else {
            __asm volatile("s_waitcnt vmcnt(0)\n\ts_barrier" ::: "memory");
        }
        const unsigned short* sA = (const unsigned short*)(smem + (kk & 1) * 16384);
        const unsigned short* sB = sA + 4096;
        bf16x8 af[4], bfr[4];
        #pragma unroll
        for (int tt = 0; tt < 4; ++tt) {
            af[tt]  = __builtin_bit_cast(bf16x8, *(const ushort8v*)(sA + (wm * 64 + tt * 16 + l16) * 32 + quad * 8));
            bfr[tt] = __builtin_bit_cast(bf16x8, *(const ushort8v*)(sB + (wn * 64 + tt * 16 + l16) * 32 + quad * 8));
        }
        #pragma unroll
        for (int mt = 0; mt < 4; ++mt)
            #pragma unroll
            for (int nt = 0; nt < 4; ++nt)
                acc[mt][nt] = __builtin_amdgcn_mfma_f32_16x16x32_bf16(af[mt], bfr[nt], acc[mt][nt], 0, 0, 0);
        __asm volatile("s_barrier" ::: "memory");   // frag reads done before next DMA lands
    }

    float b4[4];
    #pragma unroll
    for (int nt = 0; nt < 4; ++nt) b4[nt] = bias[n0 + wn * 64 + nt * 16 + l16];

    if (EPI == 0 || EPI == 2) {
        // ---- bf16 output: bounce to LDS, store packed uint4 ----
        unsigned short (*swB)[136] = (unsigned short (*)[136])smem;  // 128x136x2 = 34816B
        const int seg = n0 >> 8;                      // EPI0: 0=q 1=k 2=v (block never straddles)
        const float qs = (EPI == 0 && seg == 0) ? SCALE_ : 1.0f;
        #pragma unroll
        for (int mt = 0; mt < 4; ++mt)
            #pragma unroll
            for (int nt = 0; nt < 4; ++nt)
                #pragma unroll
                for (int r = 0; r < 4; ++r) {
                    float v = acc[mt][nt][r] + b4[nt];
                    if (EPI == 0) v *= qs; else v = gelu_t(v);
                    swB[wm * 64 + mt * 16 + quad * 4 + r][wn * 64 + nt * 16 + l16] = f2bf(v);
                }
        __syncthreads();
        if (EPI == 0) {
            unsigned short* dstp = seg == 0 ? outQ : (seg == 1 ? outK : outV);
            const int nbase = n0 & 255;
            for (int tt = tid; tt < 2048; tt += 256) {
                int row = tt >> 4, c8 = (tt & 15) * 8;
                int m = m0 + row, bw = m / NN, nw = m - bw * NN;
                int cc = nbase + c8;
                uint4 u = *(uint4*)&swB[row][c8];
                *(uint4*)&dstp[(((size_t)bw * NH_ + (cc >> 5)) * NN + nw) * HD_ + (cc & 31)] = u;
            }
        } else {
            for (int tt = tid; tt < 2048; tt += 256) {
                int row = tt >> 4, c8 = (tt & 15) * 8;
                uint4 u = *(uint4*)&swB[row][c8];
                *(uint4*)&outQ[(size_t)(m0 + row) * 1024 + n0 + c8] = u;
            }
        }
    } else {
        // ---- fp32 output: two 64-row passes through LDS, float4 stores ----
        float (*swF)[132] = (float (*)[132])smem;     // 64x132x4 = 33792B
        #pragma unroll
        for (int p = 0; p < 2; ++p) {
            __syncthreads();
            if (wm == p) {
                #pragma unroll
                for (int mt = 0; mt < 4; ++mt)
                    #pragma unroll
                    for (int nt = 0; nt < 4; ++nt)
                        #pragma unroll
                        for (int r = 0; r < 4; ++r)
                            swF[mt * 16 + quad * 4 + r][wn * 64 + nt * 16 + l16] = acc[mt][nt][r] + b4[nt];
            }
            __syncthreads();
            for (int tt = tid; tt < 2048; tt += 256) {
                int rl = tt >> 5, c4 = (tt & 31) * 4;
                size_t adr;
                if (EPI == 1) {                       // window-reverse + unshift
                    int m = m0 + p * 64 + rl, bw = m / NN, nw = m - bw * NN;
                    int b = bw >> 6, wi = bw & 63;
                    int sh = (wi >> 3) * WS_ + nw / WS_;
                    int sw = (wi & 7) * WS_ + nw % WS_;
                    int ph = sh + SS_; if (ph >= HH)  ph -= HH;
                    int pw = sw + SS_; if (pw >= WWI) pw -= WWI;
                    adr = ((size_t)b * 3136 + ph * 56 + pw) * C_ + n0 + c4;
                } else {
                    adr = (size_t)(m0 + p * 64 + rl) * C_ + n0 + c4;
                }
                float4 u = *(float4*)&swF[rl][c4];
                const float4 rr = (EPI == 1) ? *(const float4*)&resid[adr]
                                             : *(const float4*)&outF[adr];
                u.x += rr.x; u.y += rr.y; u.z += rr.z; u.w += rr.w;
                *(float4*)&outF[adr] = u;
            }
        }
    }
}

// ---------------- MFMA attention: one block per (window, head) ----------------
__global__ __launch_bounds__(256) void attn_k(
    const unsigned short* __restrict__ qb, const unsigned short* __restrict__ kb,
    const unsigned short* __restrict__ vb, const unsigned short* __restrict__ cb,
    unsigned short* __restrict__ ob)
{
    __shared__ unsigned short qs[64][40];   // Q rows (pad 40: frag reads 2-way free)
    __shared__ unsigned short ks[64][40];   // K rows
    __shared__ unsigned short vt[32][72];   // V^T: [d][j], j padded to 64 (zeroed 49..63)
    __shared__ unsigned short sp[64][72];   // P bf16, A-layout rows
    __shared__ unsigned short cbs[2408];    // bias+mask slice
    const int tid = threadIdx.x;
    const int bw = blockIdx.x >> 3, head = blockIdx.x & 7;
    const size_t base = (size_t)blockIdx.x * (NN * HD_);   // (bw*8+head)*1568

    for (int t = tid; t < 588; t += 256) {
        int seg = t / 196, idx = t - seg * 196;
        int e = idx * 8;                          // 8 shorts = 16B
        const unsigned short* src = (seg == 0 ? qb : seg == 1 ? kb : vb) + base + e;
        uint4 u = *(const uint4*)src;
        if (seg == 0)      *(uint4*)&qs[e >> 5][e & 31] = u;
        else if (seg == 1) *(uint4*)&ks[e >> 5][e & 31] = u;
        else {
            int n = e >> 5, hd = e & 31;
            const unsigned short* pu = (const unsigned short*)&u;
            #pragma unroll
            for (int uu = 0; uu < 8; ++uu) vt[hd + uu][n] = pu[uu];
        }
    }
    {
        const unsigned short* cbase = cb + (size_t)(((bw & 63) * 8 + head)) * 2408;
        for (int t = tid; t < 301; t += 256)
            *(uint4*)&cbs[t * 8] = *(const uint4*)(cbase + t * 8);
        for (int t = tid; t < 480; t += 256) vt[t / 15][NN + t % 15] = 0;  // zero j=49..63
    }
    __syncthreads();

    const int wave = tid >> 6, lane = tid & 63, quad = lane >> 4, l16 = lane & 15;
    const f32x4 zz = {};

    bf16x8 afq = __builtin_bit_cast(bf16x8, *(const ushort8v*)&qs[wave * 16 + l16][quad * 8]);
    f32x4 s4[4];
    #pragma unroll
    for (int jt = 0; jt < 4; ++jt) {
        bf16x8 bk = __builtin_bit_cast(bf16x8, *(const ushort8v*)&ks[jt * 16 + l16][quad * 8]);
        s4[jt] = __builtin_amdgcn_mfma_f32_16x16x32_bf16(afq, bk, zz, 0, 0, 0);
    }

    #pragma unroll
    for (int r = 0; r < 4; ++r) {
        int i = wave * 16 + quad * 4 + r;
        float vals[4];
        #pragma unroll
        for (int jt = 0; jt < 4; ++jt) {
            int j = jt * 16 + l16;
            vals[jt] = (i < NN && j < NN) ? s4[jt][r] + bf2f(cbs[i * NN + j]) : -1e30f;
        }
        float mx = fmaxf(fmaxf(vals[0], vals[1]), fmaxf(vals[2], vals[3]));
        #pragma unroll
        for (int o = 1; o < 16; o <<= 1) mx = fmaxf(mx, __shfl_xor(mx, o, 64));
        float e[4], sum = 0.0f;
        #pragma unroll
        for (int jt = 0; jt < 4; ++jt) { e[jt] = __expf(vals[jt] - mx); sum += e[jt]; }
        #pragma unroll
        for (int o = 1; o < 16; o <<= 1) sum += __shfl_xor(sum, o, 64);
        float inv = 1.0f / sum;
        #pragma unroll
        for (int jt = 0; jt < 4; ++jt) sp[i][jt * 16 + l16] = f2bf(e[jt] * inv);
    }
    __syncthreads();

    bf16x8 ap[2];
    #pragma unroll
    for (int kt = 0; kt < 2; ++kt)
        ap[kt] = __builtin_bit_cast(bf16x8, *(const ushort8v*)&sp[wave * 16 + l16][kt * 32 + quad * 8]);
    f32x4 o4[2] = {};
    #pragma unroll
    for (int nt = 0; nt < 2; ++nt)
        #pragma unroll
        for (int kt = 0; kt < 2; ++kt) {
            bf16x8 bv = __builtin_bit_cast(bf16x8, *(const ushort8v*)&vt[nt * 16 + l16][kt * 32 + quad * 8]);
            o4[nt] = __builtin_amdgcn_mfma_f32_16x16x32_bf16(ap[kt], bv, o4[nt], 0, 0, 0);
        }
    #pragma unroll
    for (int nt = 0; nt < 2; ++nt)
        #pragma unroll
        for (int r = 0; r < 4; ++r) {
            int i = wave * 16 + quad * 4 + r;
            if (i < NN)
                ob[((size_t)bw * NN + i) * C_ + head * HD_ + nt * 16 + l16] = f2bf(o4[nt][r]);
        }
}

extern "C" void kernel_launch(void* const* d_in, const int* in_sizes, int n_in,
                              void* d_out, int out_size, void* d_ws, size_t ws_size,
                              hipStream_t stream)
{
    const float* x     = (const float*)d_in[0];
    const float* mask  = (const float*)d_in[1];
    const float* n1g   = (const float*)d_in[2];
    const float* n1b   = (const float*)d_in[3];
    const float* qkvw  = (const float*)d_in[4];
    const float* qkvb  = (const float*)d_in[5];
    const float* relb  = (const float*)d_in[6];
    const float* projw = (const float*)d_in[7];
    const float* projb = (const float*)d_in[8];
    const float* n2g   = (const float*)d_in[9];
    const float* n2b   = (const float*)d_in[10];
    const float* fc1w  = (const float*)d_in[11];
    const float* fc1b  = (const float*)d_in[12];
    const float* fc2w  = (const float*)d_in[13];
    const float* fc2b  = (const float*)d_in[14];
    float* out = (float*)d_out;

    unsigned short* wq = (unsigned short*)d_ws;   // all weights bf16, contiguous
    unsigned short* wp = wq + 196608;
    unsigned short* w1 = wq + 262144;
    unsigned short* w2 = wq + 524288;
    unsigned short* hw = wq + 786432;             // LN1-shift-partitioned (50176,256) bf16
    unsigned short* qb = hw + 12845056;           // (1024,8,49,32) bf16
    unsigned short* kb = qb + 12845056;
    unsigned short* vb = kb + 12845056;
    unsigned short* ob = vb + 12845056;           // attn out, windowed (50176,256) bf16
    unsigned short* h2 = ob + 12845056;           // LN2 out (50176,256) bf16
    unsigned short* a1 = h2 + 12845056;           // GELU(fc1) (50176,1024) bf16
    unsigned short* cbt = a1;                     // cb aliases a1 (attn_k finishes before FC1 writes a1)

    convw_k<<<3072, 256, 0, stream>>>(qkvw, projw, fc1w, fc2w, wq);
    cb_k<<<512, 256, 0, stream>>>(mask, relb, cbt);
    ln_k<<<12544, 256, 0, stream>>>(x, n1g, n1b, hw, 1);
    gemm_k<0, 6><<<392 * 6, 256, 0, stream>>>(hw, wq, 256, qkvb, nullptr, nullptr, qb, kb, vb);
    attn_k<<<8192, 256, 0, stream>>>(qb, kb, vb, cbt, ob);
    gemm_k<1, 2><<<392 * 2, 256, 0, stream>>>(ob, wp, 256, projb, x, out, nullptr, nullptr, nullptr);
    ln_k<<<12544, 256, 0, stream>>>(out, n2g, n2b, h2, 0);
    gemm_k<2, 8><<<392 * 8, 256, 0, stream>>>(h2, w1, 256, fc1b, nullptr, nullptr, a1, nullptr, nullptr);
    gemm_k<3, 2><<<392 * 2, 256, 0, stream>>>(a1, w2, 1024, fc2b, nullptr, out, nullptr, nullptr, nullptr);
}

// Round 6
// 367.312 us; speedup vs baseline: 1.4415x; 1.0226x over previous
//
#include <hip/hip_runtime.h>
#include <cmath>

#define B_    16
#define HH    56
#define WWI   56
#define C_    256
#define NH_   8
#define WS_   7
#define SS_   3
#define HD_   32
#define NTOK  50176          // B*56*56
#define NN    49             // window size squared
#define SCALE_ 0.17677669529663689f
#define EPS_  1e-5f

typedef __bf16  bf16x8  __attribute__((ext_vector_type(8)));
typedef float   f32x4   __attribute__((ext_vector_type(4)));
typedef unsigned short ushort8v __attribute__((ext_vector_type(8)));

__device__ __forceinline__ unsigned short f2bf(float f) {
    unsigned int u = __float_as_uint(f);
    unsigned int r = u + 0x7FFFu + ((u >> 16) & 1u);   // RNE
    return (unsigned short)(r >> 16);
}
__device__ __forceinline__ float bf2f(unsigned short h) {
    return __uint_as_float(((unsigned int)h) << 16);
}
// tanh-form GELU: |err| <= ~3e-3 vs exact erf form; hw v_exp_f32 + rcp
__device__ __forceinline__ float gelu_t(float x) {
    float t = 0.7978845608028654f * (x + 0.044715f * x * x * x);
    float e = __expf(2.0f * t);
    float th = 1.0f - 2.0f * __builtin_amdgcn_rcpf(e + 1.0f);
    return 0.5f * x * (1.0f + th);
}

// async global->LDS DMA, 16B per lane; deposits at wave-uniform lds base + lane*16
__device__ __forceinline__ void gload_lds16(const unsigned short* g, unsigned short* l) {
    __builtin_amdgcn_global_load_lds(
        (const __attribute__((address_space(1))) unsigned int*)g,
        (__attribute__((address_space(3))) unsigned int*)l, 16, 0, 0);
}

// ---------------- weight fp32 -> bf16 conversion ----------------
__global__ __launch_bounds__(256) void convw_k(
    const float* __restrict__ qkvw, const float* __restrict__ projw,
    const float* __restrict__ fc1w, const float* __restrict__ fc2w,
    unsigned short* __restrict__ dst)
{
    int i = blockIdx.x * 256 + threadIdx.x;          // < 786432
    float v;
    if      (i < 196608) v = qkvw[i];
    else if (i < 262144) v = projw[i - 196608];
    else if (i < 524288) v = fc1w[i - 262144];
    else                 v = fc2w[i - 524288];
    dst[i] = f2bf(v);
}

// ---------------- combined rel-bias + shift-mask table, bf16 ----------------
__global__ __launch_bounds__(256) void cb_k(
    const float* __restrict__ mask, const float* __restrict__ relb,
    unsigned short* __restrict__ cb)
{
    int s = blockIdx.x;                 // 512 slices = 64 windows * 8 heads
    int wi = s >> 3, head = s & 7;
    for (int p = threadIdx.x; p < 2408; p += 256) {
        float v = 0.0f;
        if (p < 2401) {
            int i = p / NN, j = p - i * NN;
            int di = i / 7 - j / 7 + 6, dj = i % 7 - j % 7 + 6;
            v = relb[(di * 13 + dj) * NH_ + head] + mask[(size_t)wi * 2401 + p];
        }
        cb[(size_t)s * 2408 + p] = f2bf(v);
    }
}

// ---------------- LayerNorm (+optional shift+window-partition) ----------------
__global__ __launch_bounds__(256) void ln_k(
    const float* __restrict__ x, const float* __restrict__ g,
    const float* __restrict__ bta, unsigned short* __restrict__ dst, int shifted)
{
    int wave = threadIdx.x >> 6, lane = threadIdx.x & 63;
    int tok = blockIdx.x * 4 + wave;                  // < 50176
    const float4 v = *(const float4*)(x + (size_t)tok * C_ + lane * 4);
    float s = v.x + v.y + v.z + v.w;
    float q = v.x*v.x + v.y*v.y + v.z*v.z + v.w*v.w;
    for (int o = 32; o > 0; o >>= 1) { s += __shfl_xor(s, o, 64); q += __shfl_xor(q, o, 64); }
    float mu  = s * (1.0f / C_);
    float var = q * (1.0f / C_) - mu * mu;
    float rs  = rsqrtf(var + EPS_);
    float4 gg = *(const float4*)(g   + lane * 4);
    float4 bb = *(const float4*)(bta + lane * 4);
    float y0 = (v.x - mu) * rs * gg.x + bb.x;
    float y1 = (v.y - mu) * rs * gg.y + bb.y;
    float y2 = (v.z - mu) * rs * gg.z + bb.z;
    float y3 = (v.w - mu) * rs * gg.w + bb.w;
    size_t di;
    if (shifted) {
        int b = tok / 3136, p = tok % 3136;
        int ph = p / 56, pw = p % 56;
        int sh = ph - SS_; if (sh < 0) sh += HH;
        int sw = pw - SS_; if (sw < 0) sw += WWI;
        int bw = b * 64 + (sh / WS_) * 8 + (sw / WS_);
        int n  = (sh % WS_) * WS_ + (sw % WS_);
        di = ((size_t)bw * NN + n) * C_ + lane * 4;
    } else {
        di = (size_t)tok * C_ + lane * 4;
    }
    unsigned int lo = (unsigned int)f2bf(y0) | ((unsigned int)f2bf(y1) << 16);
    unsigned int hi = (unsigned int)f2bf(y2) | ((unsigned int)f2bf(y3) << 16);
    uint2 u; u.x = lo; u.y = hi;
    *(uint2*)(dst + di) = u;
}

// ---------------- MFMA GEMM, 128x128 tile, BK=32, depth-3 pipelined DMA ------
// XCD-locality swizzle: 1-D grid of 392*NT blocks; xcd = lin&7 owns m-tiles
// [xcd*49, xcd*49+49), walked n-fastest so A-strips are fetched ~once per XCD.
// Pipeline: 3 staging buffers; issue tile k+2, wait vmcnt(8) (tile k landed,
// k+1/k+2 stay in flight across the barrier), consume tile k.
template<int EPI, int NT>
__global__ __launch_bounds__(256) void gemm_k(
    const unsigned short* __restrict__ A, const unsigned short* __restrict__ Bt,
    int K, const float* __restrict__ bias,
    const float* __restrict__ resid, float* __restrict__ outF,
    unsigned short* __restrict__ outQ, unsigned short* __restrict__ outK,
    unsigned short* __restrict__ outV)
{
    // smem: 3 x 16KB staging buffers; epilogue bounce overlays [0, 34816)
    __shared__ __align__(16) unsigned char smem[49152];
    const int tid = threadIdx.x;
    const int lin = blockIdx.x;
    const int xcd = lin & 7, t = lin >> 3;
    const int m0 = (xcd * 49 + t / NT) * 128;
    const int n0 = (t % NT) * 128;
    const int wave = tid >> 6, lane = tid & 63, quad = lane >> 4, l16 = lane & 15;
    const int wm = wave >> 1, wn = wave & 1;
    const int r0 = tid >> 2, c0 = (tid & 3) * 8;   // staging row/col (shorts)

    const size_t gA0 = (size_t)(m0 + r0) * K + c0;
    const size_t gA1 = (size_t)(m0 + r0 + 64) * K + c0;
    const size_t gB0 = (size_t)(n0 + r0) * K + c0;
    const size_t gB1 = (size_t)(n0 + r0 + 64) * K + c0;
    const int woff = wave * 512;

    f32x4 acc[4][4] = {};
    const int nk = K >> 5;
    // pre-issue tiles 0,1 into buffers 0,1
    #pragma unroll
    for (int p = 0; p < 2; ++p) {
        unsigned short* sA = (unsigned short*)(smem + p * 16384);
        unsigned short* sB = sA + 4096;
        const int kp = p << 5;
        gload_lds16(A + gA0 + kp, sA + woff);
        gload_lds16(A + gA1 + kp, sA + woff + 2048);
        gload_lds16(Bt + gB0 + kp, sB + woff);
        gload_lds16(Bt + gB1 + kp, sB + woff + 2048);
    }
    int bufc = 0;                                  // buffer holding tile kk
    for (int kk = 0; kk < nk; ++kk) {
        if (kk + 2 < nk) {                         // prefetch tile kk+2
            int bufn = bufc + 2; if (bufn >= 3) bufn -= 3;
            unsigned short* sA = (unsigned short*)(smem + bufn * 16384);
            unsigned short* sB = sA + 4096;
            const int k2 = (kk + 2) << 5;
            gload_lds16(A + gA0 + k2, sA + woff);
            gload_lds16(A + gA1 + k2, sA + woff + 2048);
            gload_lds16(Bt + gB0 + k2, sB + woff);
            gload_lds16(Bt + gB1 + k2, sB + woff + 2048);
            __asm volatile("s_waitcnt vmcnt(8)\n\ts_barrier" ::: "memory");
        } else if (kk + 1 < nk) {
            __asm volatile("s_waitcnt vmcnt(4)\n\ts_barrier" ::: "memory");
        } else {
            __asm volatile("s_waitcnt vmcnt(0)\n\ts_barrier" ::: "memory");
        }
        const unsigned short* sA = (const unsigned short*)(smem + bufc * 16384);
        const unsigned short* sB = sA + 4096;
        bf16x8 af[4], bfr[4];
        #pragma unroll
        for (int tt = 0; tt < 4; ++tt) {
            af[tt]  = __builtin_bit_cast(bf16x8, *(const ushort8v*)(sA + (wm * 64 + tt * 16 + l16) * 32 + quad * 8));
            bfr[tt] = __builtin_bit_cast(bf16x8, *(const ushort8v*)(sB + (wn * 64 + tt * 16 + l16) * 32 + quad * 8));
        }
        #pragma unroll
        for (int mt = 0; mt < 4; ++mt)
            #pragma unroll
            for (int nt = 0; nt < 4; ++nt)
                acc[mt][nt] = __builtin_amdgcn_mfma_f32_16x16x32_bf16(af[mt], bfr[nt], acc[mt][nt], 0, 0, 0);
        __asm volatile("s_barrier" ::: "memory");   // frag reads done before reuse of this buffer
        if (++bufc == 3) bufc = 0;
    }

    float b4[4];
    #pragma unroll
    for (int nt = 0; nt < 4; ++nt) b4[nt] = bias[n0 + wn * 64 + nt * 16 + l16];

    if (EPI == 0 || EPI == 2) {
        // ---- bf16 output: bounce to LDS, store packed uint4 ----
        unsigned short (*swB)[136] = (unsigned short (*)[136])smem;  // 128x136x2 = 34816B
        const int seg = n0 >> 8;                      // EPI0: 0=q 1=k 2=v (block never straddles)
        const float qs = (EPI == 0 && seg == 0) ? SCALE_ : 1.0f;
        #pragma unroll
        for (int mt = 0; mt < 4; ++mt)
            #pragma unroll
            for (int nt = 0; nt < 4; ++nt)
                #pragma unroll
                for (int r = 0; r < 4; ++r) {
                    float v = acc[mt][nt][r] + b4[nt];
                    if (EPI == 0) v *= qs; else v = gelu_t(v);
                    swB[wm * 64 + mt * 16 + quad * 4 + r][wn * 64 + nt * 16 + l16] = f2bf(v);
                }
        __syncthreads();
        if (EPI == 0) {
            unsigned short* dstp = seg == 0 ? outQ : (seg == 1 ? outK : outV);
            const int nbase = n0 & 255;
            for (int tt = tid; tt < 2048; tt += 256) {
                int row = tt >> 4, c8 = (tt & 15) * 8;
                int m = m0 + row, bw = m / NN, nw = m - bw * NN;
                int cc = nbase + c8;
                uint4 u = *(uint4*)&swB[row][c8];
                *(uint4*)&dstp[(((size_t)bw * NH_ + (cc >> 5)) * NN + nw) * HD_ + (cc & 31)] = u;
            }
        } else {
            for (int tt = tid; tt < 2048; tt += 256) {
                int row = tt >> 4, c8 = (tt & 15) * 8;
                uint4 u = *(uint4*)&swB[row][c8];
                *(uint4*)&outQ[(size_t)(m0 + row) * 1024 + n0 + c8] = u;
            }
        }
    } else {
        // ---- fp32 output: two 64-row passes through LDS, float4 stores ----
        float (*swF)[132] = (float (*)[132])smem;     // 64x132x4 = 33792B
        #pragma unroll
        for (int p = 0; p < 2; ++p) {
            __syncthreads();
            if (wm == p) {
                #pragma unroll
                for (int mt = 0; mt < 4; ++mt)
                    #pragma unroll
                    for (int nt = 0; nt < 4; ++nt)
                        #pragma unroll
                        for (int r = 0; r < 4; ++r)
                            swF[mt * 16 + quad * 4 + r][wn * 64 + nt * 16 + l16] = acc[mt][nt][r] + b4[nt];
            }
            __syncthreads();
            for (int tt = tid; tt < 2048; tt += 256) {
                int rl = tt >> 5, c4 = (tt & 31) * 4;
                size_t adr;
                if (EPI == 1) {                       // window-reverse + unshift
                    int m = m0 + p * 64 + rl, bw = m / NN, nw = m - bw * NN;
                    int b = bw >> 6, wi = bw & 63;
                    int sh = (wi >> 3) * WS_ + nw / WS_;
                    int sw = (wi & 7) * WS_ + nw % WS_;
                    int ph = sh + SS_; if (ph >= HH)  ph -= HH;
                    int pw = sw + SS_; if (pw >= WWI) pw -= WWI;
                    adr = ((size_t)b * 3136 + ph * 56 + pw) * C_ + n0 + c4;
                } else {
                    adr = (size_t)(m0 + p * 64 + rl) * C_ + n0 + c4;
                }
                float4 u = *(float4*)&swF[rl][c4];
                const float4 rr = (EPI == 1) ? *(const float4*)&resid[adr]
                                             : *(const float4*)&outF[adr];
                u.x += rr.x; u.y += rr.y; u.z += rr.z; u.w += rr.w;
                *(float4*)&outF[adr] = u;
            }
        }
    }
}

// ---------------- MFMA attention: one block per (window, head) ----------------
__global__ __launch_bounds__(256) void attn_k(
    const unsigned short* __restrict__ qb, const unsigned short* __restrict__ kb,
    const unsigned short* __restrict__ vb, const unsigned short* __restrict__ cb,
    unsigned short* __restrict__ ob)
{
    __shared__ unsigned short qs[64][40];   // Q rows (pad 40: frag reads 2-way free)
    __shared__ unsigned short ks[64][40];   // K rows
    __shared__ unsigned short vt[32][72];   // V^T: [d][j], j padded to 64 (zeroed 49..63)
    __shared__ unsigned short sp[64][72];   // P bf16, A-layout rows
    __shared__ unsigned short cbs[2408];    // bias+mask slice
    const int tid = threadIdx.x;
    const int bw = blockIdx.x >> 3, head = blockIdx.x & 7;
    const size_t base = (size_t)blockIdx.x * (NN * HD_);   // (bw*8+head)*1568

    for (int t = tid; t < 588; t += 256) {
        int seg = t / 196, idx = t - seg * 196;
        int e = idx * 8;                          // 8 shorts = 16B
        const unsigned short* src = (seg == 0 ? qb : seg == 1 ? kb : vb) + base + e;
        uint4 u = *(const uint4*)src;
        if (seg == 0)      *(uint4*)&qs[e >> 5][e & 31] = u;
        else if (seg == 1) *(uint4*)&ks[e >> 5][e & 31] = u;
        else {
            int n = e >> 5, hd = e & 31;
            const unsigned short* pu = (const unsigned short*)&u;
            #pragma unroll
            for (int uu = 0; uu < 8; ++uu) vt[hd + uu][n] = pu[uu];
        }
    }
    {
        const unsigned short* cbase = cb + (size_t)(((bw & 63) * 8 + head)) * 2408;
        for (int t = tid; t < 301; t += 256)
            *(uint4*)&cbs[t * 8] = *(const uint4*)(cbase + t * 8);
        for (int t = tid; t < 480; t += 256) vt[t / 15][NN + t % 15] = 0;  // zero j=49..63
    }
    __syncthreads();

    const int wave = tid >> 6, lane = tid & 63, quad = lane >> 4, l16 = lane & 15;
    const f32x4 zz = {};

    bf16x8 afq = __builtin_bit_cast(bf16x8, *(const ushort8v*)&qs[wave * 16 + l16][quad * 8]);
    f32x4 s4[4];
    #pragma unroll
    for (int jt = 0; jt < 4; ++jt) {
        bf16x8 bk = __builtin_bit_cast(bf16x8, *(const ushort8v*)&ks[jt * 16 + l16][quad * 8]);
        s4[jt] = __builtin_amdgcn_mfma_f32_16x16x32_bf16(afq, bk, zz, 0, 0, 0);
    }

    #pragma unroll
    for (int r = 0; r < 4; ++r) {
        int i = wave * 16 + quad * 4 + r;
        float vals[4];
        #pragma unroll
        for (int jt = 0; jt < 4; ++jt) {
            int j = jt * 16 + l16;
            vals[jt] = (i < NN && j < NN) ? s4[jt][r] + bf2f(cbs[i * NN + j]) : -1e30f;
        }
        float mx = fmaxf(fmaxf(vals[0], vals[1]), fmaxf(vals[2], vals[3]));
        #pragma unroll
        for (int o = 1; o < 16; o <<= 1) mx = fmaxf(mx, __shfl_xor(mx, o, 64));
        float e[4], sum = 0.0f;
        #pragma unroll
        for (int jt = 0; jt < 4; ++jt) { e[jt] = __expf(vals[jt] - mx); sum += e[jt]; }
        #pragma unroll
        for (int o = 1; o < 16; o <<= 1) sum += __shfl_xor(sum, o, 64);
        float inv = 1.0f / sum;
        #pragma unroll
        for (int jt = 0; jt < 4; ++jt) sp[i][jt * 16 + l16] = f2bf(e[jt] * inv);
    }
    __syncthreads();

    bf16x8 ap[2];
    #pragma unroll
    for (int kt = 0; kt < 2; ++kt)
        ap[kt] = __builtin_bit_cast(bf16x8, *(const ushort8v*)&sp[wave * 16 + l16][kt * 32 + quad * 8]);
    f32x4 o4[2] = {};
    #pragma unroll
    for (int nt = 0; nt < 2; ++nt)
        #pragma unroll
        for (int kt = 0; kt < 2; ++kt) {
            bf16x8 bv = __builtin_bit_cast(bf16x8, *(const ushort8v*)&vt[nt * 16 + l16][kt * 32 + quad * 8]);
            o4[nt] = __builtin_amdgcn_mfma_f32_16x16x32_bf16(ap[kt], bv, o4[nt], 0, 0, 0);
        }
    #pragma unroll
    for (int nt = 0; nt < 2; ++nt)
        #pragma unroll
        for (int r = 0; r < 4; ++r) {
            int i = wave * 16 + quad * 4 + r;
            if (i < NN)
                ob[((size_t)bw * NN + i) * C_ + head * HD_ + nt * 16 + l16] = f2bf(o4[nt][r]);
        }
}

extern "C" void kernel_launch(void* const* d_in, const int* in_sizes, int n_in,
                              void* d_out, int out_size, void* d_ws, size_t ws_size,
                              hipStream_t stream)
{
    const float* x     = (const float*)d_in[0];
    const float* mask  = (const float*)d_in[1];
    const float* n1g   = (const float*)d_in[2];
    const float* n1b   = (const float*)d_in[3];
    const float* qkvw  = (const float*)d_in[4];
    const float* qkvb  = (const float*)d_in[5];
    const float* relb  = (const float*)d_in[6];
    const float* projw = (const float*)d_in[7];
    const float* projb = (const float*)d_in[8];
    const float* n2g   = (const float*)d_in[9];
    const float* n2b   = (const float*)d_in[10];
    const float* fc1w  = (const float*)d_in[11];
    const float* fc1b  = (const float*)d_in[12];
    const float* fc2w  = (const float*)d_in[13];
    const float* fc2b  = (const float*)d_in[14];
    float* out = (float*)d_out;

    unsigned short* wq = (unsigned short*)d_ws;   // all weights bf16, contiguous
    unsigned short* wp = wq + 196608;
    unsigned short* w1 = wq + 262144;
    unsigned short* w2 = wq + 524288;
    unsigned short* hw = wq + 786432;             // LN1-shift-partitioned (50176,256) bf16
    unsigned short* qb = hw + 12845056;           // (1024,8,49,32) bf16
    unsigned short* kb = qb + 12845056;
    unsigned short* vb = kb + 12845056;
    unsigned short* ob = vb + 12845056;           // attn out, windowed (50176,256) bf16
    unsigned short* h2 = ob + 12845056;           // LN2 out (50176,256) bf16
    unsigned short* a1 = h2 + 12845056;           // GELU(fc1) (50176,1024) bf16
    unsigned short* cbt = a1;                     // cb aliases a1 (attn_k finishes before FC1 writes a1)

    convw_k<<<3072, 256, 0, stream>>>(qkvw, projw, fc1w, fc2w, wq);
    cb_k<<<512, 256, 0, stream>>>(mask, relb, cbt);
    ln_k<<<12544, 256, 0, stream>>>(x, n1g, n1b, hw, 1);
    gemm_k<0, 6><<<392 * 6, 256, 0, stream>>>(hw, wq, 256, qkvb, nullptr, nullptr, qb, kb, vb);
    attn_k<<<8192, 256, 0, stream>>>(qb, kb, vb, cbt, ob);
    gemm_k<1, 2><<<392 * 2, 256, 0, stream>>>(ob, wp, 256, projb, x, out, nullptr, nullptr, nullptr);
    ln_k<<<12544, 256, 0, stream>>>(out, n2g, n2b, h2, 0);
    gemm_k<2, 8><<<392 * 8, 256, 0, stream>>>(h2, w1, 256, fc1b, nullptr, nullptr, a1, nullptr, nullptr);
    gemm_k<3, 2><<<392 * 2, 256, 0, stream>>>(a1, w2, 1024, fc2b, nullptr, out, nullptr, nullptr, nullptr);
}